// Round 8
// baseline (2839.163 us; speedup 1.0000x reference)
//
#include <hip/hip_runtime.h>
#include <hip/hip_bf16.h>

// Problem constants
#define T_STEPS 512
#define BATCH   64
#define IDIM    1024
#define HDIM    1024
#define GDIM    4096   // 4*HDIM
#define UPB     16     // hidden units per recurrence block
#define LSTM_BLOCKS 64 // HDIM / UPB

typedef __attribute__((ext_vector_type(8))) short short8;
typedef __attribute__((ext_vector_type(8))) unsigned short ushort8;
typedef __attribute__((ext_vector_type(4))) float f32x4;

static __device__ __forceinline__ unsigned short f2bf(float f) {
    union { float f; unsigned u; } x; x.f = f;
    unsigned r = x.u + 0x7fffu + ((x.u >> 16) & 1u);  // round-to-nearest-even
    return (unsigned short)(r >> 16);
}

static __device__ __forceinline__ short8 pack8(const float* p) {
    float4 v0 = *reinterpret_cast<const float4*>(p);
    float4 v1 = *reinterpret_cast<const float4*>(p + 4);
    short8 t;
    t[0]=(short)f2bf(v0.x); t[1]=(short)f2bf(v0.y);
    t[2]=(short)f2bf(v0.z); t[3]=(short)f2bf(v0.w);
    t[4]=(short)f2bf(v1.x); t[5]=(short)f2bf(v1.y);
    t[6]=(short)f2bf(v1.z); t[7]=(short)f2bf(v1.w);
    return t;
}

// 16B coherent-bypass load/store (skip L1/L2; MALL coherence point).
static __device__ __forceinline__ short8 ldg16(const unsigned short* p) {
    short8 d;
    asm volatile("global_load_dwordx4 %0, %1, off sc0 sc1" : "=v"(d) : "v"(p));
    return d;
}
static __device__ __forceinline__ void stg16(unsigned short* p, ushort8 v) {
    asm volatile("global_store_dwordx4 %0, %1, off sc0 sc1"
                 :: "v"(p), "v"(v) : "memory");
}
static __device__ __forceinline__ unsigned ldflag(const unsigned* p) {
    unsigned d;
    asm volatile("global_load_dword %0, %1, off sc0 sc1" : "=v"(d) : "v"(p));
    return d;
}
static __device__ __forceinline__ void stflag(unsigned* p, unsigned v) {
    asm volatile("global_store_dword %0, %1, off sc0 sc1"
                 :: "v"(p), "v"(v) : "memory");
}

// counted vmcnt wait + scheduler fence (keeps MFMAs from hoisting above it)
#define VMW(n) do { asm volatile("s_waitcnt vmcnt(" #n ")"); \
                    __builtin_amdgcn_sched_barrier(0); } while (0)

// fast activations: v_exp_f32 computes 2^x; v_rcp_f32 ~1ULP
static __device__ __forceinline__ float fexp2(float x) {
    float r; asm("v_exp_f32 %0, %1" : "=v"(r) : "v"(x)); return r;
}
static __device__ __forceinline__ float frcp(float x) {
    float r; asm("v_rcp_f32 %0, %1" : "=v"(r) : "v"(x)); return r;
}
static __device__ __forceinline__ float fsigmoid(float x) {
    return frcp(1.f + fexp2(-1.4426950408889634f * x));
}
static __device__ __forceinline__ float ftanh(float x) {
    return 2.f * frcp(1.f + fexp2(-2.8853900817779268f * x)) - 1.f;
}

// ---------------------------------------------------------------------------
// Kernel 0: h0 (fp32 [B,H]) -> swizzled bf16 buffer 0.
// 16B chunk index (Rtile*32 + s)*64 + lane holds
//   h[Rtile*16 + (lane&15)][s*32 + (lane>>4)*8 .. +8)
// ---------------------------------------------------------------------------
__global__ void k_h0_swz(const float* __restrict__ h0,
                         unsigned short* __restrict__ hbuf0) {
    int i = blockIdx.x * 256 + threadIdx.x;   // 8192 threads: 64 rows x 128 chunks
    int m  = i >> 7;
    int hh = i & 127;                         // u = hh*8
    const float* src = h0 + (size_t)m * HDIM + hh * 8;
    float4 a = *reinterpret_cast<const float4*>(src);
    float4 c = *reinterpret_cast<const float4*>(src + 4);
    ushort8 v;
    v[0]=f2bf(a.x); v[1]=f2bf(a.y); v[2]=f2bf(a.z); v[3]=f2bf(a.w);
    v[4]=f2bf(c.x); v[5]=f2bf(c.y); v[6]=f2bf(c.z); v[7]=f2bf(c.w);
    size_t dst16 = ((size_t)(m >> 4) * 32 + (hh >> 2)) * 64 + (m & 15) + 16 * (hh & 3);
    *reinterpret_cast<ushort8*>(hbuf0 + dst16 * 8) = v;  // kernel-end flush -> MALL
}

// ---------------------------------------------------------------------------
// Kernel 1: gx = input @ W_x^T + b_x + b_h   (unchanged; passed rounds 1-7)
// ---------------------------------------------------------------------------
__global__ __launch_bounds__(256) void k_gx_gemm(
        const float* __restrict__ X, const float* __restrict__ Wx,
        const float* __restrict__ bx, const float* __restrict__ bh,
        float* __restrict__ gx) {
    __shared__ unsigned short As[128][40];
    __shared__ unsigned short Bs[128][40];

    const int bid  = blockIdx.x;
    const int nt   = bid & 31;     // 32 N tiles
    const int mt   = bid >> 5;     // 256 M tiles
    const int tid  = threadIdx.x;
    const int lane = tid & 63;
    const int w    = tid >> 6;
    const int wm   = (w >> 1) * 64;
    const int wn   = (w & 1) * 64;
    const int lmod = lane & 15;
    const int lk8  = (lane >> 4) * 8;

    f32x4 acc[4][4] = {};

    const int srow = tid >> 1;
    const int scol = (tid & 1) * 16;
    const float* Abase = X  + (size_t)(mt * 128 + srow) * 1024 + scol;
    const float* Bbase = Wx + (size_t)(nt * 128 + srow) * 1024 + scol;

    for (int k0 = 0; k0 < 1024; k0 += 32) {
        const float4* a4 = reinterpret_cast<const float4*>(Abase + k0);
        const float4* b4 = reinterpret_cast<const float4*>(Bbase + k0);
        ushort8 pa[2], pb[2];
#pragma unroll
        for (int h = 0; h < 2; ++h) {
            float4 v0 = a4[h * 2], v1 = a4[h * 2 + 1];
            ushort8 t;
            t[0]=f2bf(v0.x); t[1]=f2bf(v0.y); t[2]=f2bf(v0.z); t[3]=f2bf(v0.w);
            t[4]=f2bf(v1.x); t[5]=f2bf(v1.y); t[6]=f2bf(v1.z); t[7]=f2bf(v1.w);
            pa[h] = t;
            float4 u0 = b4[h * 2], u1 = b4[h * 2 + 1];
            ushort8 s;
            s[0]=f2bf(u0.x); s[1]=f2bf(u0.y); s[2]=f2bf(u0.z); s[3]=f2bf(u0.w);
            s[4]=f2bf(u1.x); s[5]=f2bf(u1.y); s[6]=f2bf(u1.z); s[7]=f2bf(u1.w);
            pb[h] = s;
        }
        __syncthreads();
        *reinterpret_cast<ushort8*>(&As[srow][scol])     = pa[0];
        *reinterpret_cast<ushort8*>(&As[srow][scol + 8]) = pa[1];
        *reinterpret_cast<ushort8*>(&Bs[srow][scol])     = pb[0];
        *reinterpret_cast<ushort8*>(&Bs[srow][scol + 8]) = pb[1];
        __syncthreads();

        short8 af[4], bf_[4];
#pragma unroll
        for (int i = 0; i < 4; ++i)
            af[i] = *reinterpret_cast<const short8*>(&As[wm + i * 16 + lmod][lk8]);
#pragma unroll
        for (int i = 0; i < 4; ++i)
            bf_[i] = *reinterpret_cast<const short8*>(&Bs[wn + i * 16 + lmod][lk8]);
#pragma unroll
        for (int i = 0; i < 4; ++i)
#pragma unroll
            for (int j = 0; j < 4; ++j)
                acc[i][j] = __builtin_amdgcn_mfma_f32_16x16x32_bf16(
                                af[i], bf_[j], acc[i][j], 0, 0, 0);
    }

#pragma unroll
    for (int j = 0; j < 4; ++j) {
        int n = nt * 128 + wn + j * 16 + lmod;
        float bb = bx[n] + bh[n];
#pragma unroll
        for (int i = 0; i < 4; ++i) {
            int mbase = mt * 128 + wm + i * 16 + (lane >> 4) * 4;
#pragma unroll
            for (int r = 0; r < 4; ++r)
                gx[(size_t)(mbase + r) * GDIM + n] = acc[i][j][r] + bb;
        }
    }
}

// ---------------------------------------------------------------------------
// Kernel 2: persistent LSTM recurrence.
// 64 blocks x 256 threads. Block b owns hidden units [b*16, b*16+16) = 64
// gate-cols. Wave (rh,kh): rows rh*32..+32 x 64 cols x K-half kh*512..+512;
// disjoint A chunks. W_h K-half in registers (AGPR-backed; 1 wave/SIMD).
// Round 8: per-storing-wave flags (2/block, 128 total) -- each storing wave
// drains its OWN 16B h stores and posts its flag immediately (no third block
// sync). Consumer wave (rh,kh) polls exactly the 32 flags it reads from
// (producers of its K-half, row-half sw=rh). Collectively the 4 waves verify
// all 128 flags before gs-sync, preserving double-buffer write safety.
// ---------------------------------------------------------------------------
__global__ __launch_bounds__(256, 1) void k_lstm(
        const float* __restrict__ gx, const float* __restrict__ Wh,
        const float* __restrict__ cinit, float* __restrict__ out,
        unsigned short* __restrict__ hbuf, unsigned* __restrict__ bar) {
    __shared__ __align__(16) float gs[2][64][68];         // 35 KB
    __shared__ __align__(16) unsigned short hs[64][16];   // 2 KB

    const int b    = blockIdx.x;     // 64
    const int tid  = threadIdx.x;    // 256
    const int lane = tid & 63;
    const int w    = tid >> 6;       // 0..3
    const int rh   = w >> 1;         // batch-row half
    const int kh   = w & 1;          // K half
    const int l15  = lane & 15;
    const int lk8  = (lane >> 4) * 8;

    // ---- W_h (64 cols x K-half) -> registers. breg[cg*16+ks]:
    //      col = cg*16 + l15 (gate cg, unit l15), k = kh*512 + ks*32 + lk8
    short8 breg[64];
#pragma unroll
    for (int cg = 0; cg < 4; ++cg) {
        const float* wb = Wh + ((size_t)(cg * HDIM + b * UPB + l15)) * HDIM
                        + kh * 512 + lk8;
#pragma unroll
        for (int ks = 0; ks < 16; ++ks)
            breg[cg * 16 + ks] = pack8(wb + ks * 32);
    }

    // ---- per-thread gate ownership: unit u, batch rows mg*4..mg*4+3
    const int u   = tid & 15;
    const int mg  = tid >> 4;        // 0..15
    const int col = b * UPB + u;     // global hidden index

    float c_reg[4];
#pragma unroll
    for (int r = 0; r < 4; ++r)
        c_reg[r] = cinit[(size_t)(mg * 4 + r) * HDIM + col];

    // gx for t=0
    float gxv[4][4];
#pragma unroll
    for (int r = 0; r < 4; ++r)
#pragma unroll
        for (int g = 0; g < 4; ++g)
            gxv[r][g] = gx[(size_t)(mg * 4 + r) * GDIM + g * HDIM + col];

    __syncthreads();   // also drains the gxv/c_reg loads: t=0 poll is clean

    // this wave's flag subset: producers p = kh*32 + (lane&31), row-half sw=rh
    const unsigned* fb = &bar[(((kh << 5) | (lane & 31)) * 2 + rh) * 32];

    for (int t = 0; t < T_STEPS; ++t) {
        // ---- tight poll (clean: no outstanding vmem when we get here)
        while (true) {
            unsigned v = ldflag(fb);
            VMW(0);
            if (__all((int)(v >= (unsigned)t))) break;
        }
        asm volatile("" ::: "memory");   // keep bypass loads below the poll

        // ---- A stream: chunks (rh*2+rp)*32 + kh*16 + ks, contiguous 1KB each
        const unsigned short* hA2 = hbuf + (size_t)(t & 1) * (BATCH * HDIM)
                                  + ((size_t)rh * 64 + kh * 16) * 512 + lane * 8;
        short8 st[24];
#define SLOT(i) ((i) < 24 ? (i) : (i) - 24)
#define ISSK(ks) do { \
        st[SLOT((ks) * 2)]     = ldg16(hA2 + (ks) * 512);          \
        st[SLOT((ks) * 2 + 1)] = ldg16(hA2 + 16384 + (ks) * 512);  \
    } while (0)
#define CONS1(ks) do { \
        short8 a0 = st[SLOT((ks) * 2)], a1 = st[SLOT((ks) * 2 + 1)]; \
        accP0 = __builtin_amdgcn_mfma_f32_16x16x32_bf16(a0, breg[(ks)],      accP0, 0, 0, 0); \
        accP1 = __builtin_amdgcn_mfma_f32_16x16x32_bf16(a0, breg[16 + (ks)], accP1, 0, 0, 0); \
        accP2 = __builtin_amdgcn_mfma_f32_16x16x32_bf16(a0, breg[32 + (ks)], accP2, 0, 0, 0); \
        accP3 = __builtin_amdgcn_mfma_f32_16x16x32_bf16(a0, breg[48 + (ks)], accP3, 0, 0, 0); \
        accQ0 = __builtin_amdgcn_mfma_f32_16x16x32_bf16(a1, breg[(ks)],      accQ0, 0, 0, 0); \
        accQ1 = __builtin_amdgcn_mfma_f32_16x16x32_bf16(a1, breg[16 + (ks)], accQ1, 0, 0, 0); \
        accQ2 = __builtin_amdgcn_mfma_f32_16x16x32_bf16(a1, breg[32 + (ks)], accQ2, 0, 0, 0); \
        accQ3 = __builtin_amdgcn_mfma_f32_16x16x32_bf16(a1, breg[48 + (ks)], accQ3, 0, 0, 0); \
    } while (0)

        f32x4 accP0 = {}, accP1 = {}, accP2 = {}, accP3 = {};
        f32x4 accQ0 = {}, accQ1 = {}, accQ2 = {}, accQ3 = {};
        ISSK(0); ISSK(1); ISSK(2);  ISSK(3);  ISSK(4);  ISSK(5);
        ISSK(6); ISSK(7); ISSK(8);  ISSK(9);  ISSK(10); ISSK(11);   // 24 in flight
        VMW(16); CONS1(0);  CONS1(1);  CONS1(2);  CONS1(3);
        ISSK(12); ISSK(13); ISSK(14); ISSK(15);
        VMW(16); CONS1(4);  CONS1(5);  CONS1(6);  CONS1(7);
        VMW(8);  CONS1(8);  CONS1(9);  CONS1(10); CONS1(11);
        VMW(0);  CONS1(12); CONS1(13); CONS1(14); CONS1(15);
#undef SLOT
#undef ISSK
#undef CONS1

        // ---- partials -> gs[kh]
        {
            const int gr = rh * 32 + (lane >> 4) * 4;
#pragma unroll
            for (int r = 0; r < 4; ++r) {
                gs[kh][gr + r][l15]           = accP0[r];
                gs[kh][gr + r][16 + l15]      = accP1[r];
                gs[kh][gr + r][32 + l15]      = accP2[r];
                gs[kh][gr + r][48 + l15]      = accP3[r];
                gs[kh][gr + 16 + r][l15]      = accQ0[r];
                gs[kh][gr + 16 + r][16 + l15] = accQ1[r];
                gs[kh][gr + 16 + r][32 + l15] = accQ2[r];
                gs[kh][gr + 16 + r][48 + l15] = accQ3[r];
            }
        }
        __syncthreads();   // joins all waves: all 128 flags verified >= t

        // ---- gates + state update (all 256 threads, 4 batch rows each)
        float hv[4];
#pragma unroll
        for (int r = 0; r < 4; ++r) {
            const int m = mg * 4 + r;
            float xi = gxv[r][0] + gs[0][m][u]      + gs[1][m][u];
            float xf = gxv[r][1] + gs[0][m][16 + u] + gs[1][m][16 + u];
            float xo = gxv[r][2] + gs[0][m][32 + u] + gs[1][m][32 + u];
            float xn = gxv[r][3] + gs[0][m][48 + u] + gs[1][m][48 + u];
            float ig = fsigmoid(xi);
            float fg = fsigmoid(xf);
            float og = fsigmoid(xo);
            float ng = ftanh(xn);
            c_reg[r] = fg * c_reg[r] + ig * ng;
            float h = og * ftanh(c_reg[r]);
            hv[r] = h;
            hs[m][u] = f2bf(h);
        }

        if (t == T_STEPS - 1) {
            size_t fin = (size_t)T_STEPS * BATCH * HDIM;
#pragma unroll
            for (int r = 0; r < 4; ++r) {
                const int m = mg * 4 + r;
                out[((size_t)t * BATCH + m) * HDIM + col] = hv[r];
                out[fin + (size_t)m * HDIM + col] = hv[r];                           // h_fin
                out[fin + (size_t)BATCH * HDIM + (size_t)m * HDIM + col] = c_reg[r]; // c_fin
            }
            break;
        }

        __syncthreads();   // hs complete

        // ---- packed swizzled h store; storing wave drains ITS stores and
        //      posts its own flag (no block-wide sync on the posting path)
        if (w < 2) {
            const int m  = tid >> 1;          // wave 0: rows 0-31 (sw=0); wave 1: 32-63
            const int hh = tid & 1;
            ushort8 v = *reinterpret_cast<const ushort8*>(&hs[m][hh * 8]);
            size_t dst16 = ((size_t)(m >> 4) * 32 + (b >> 1)) * 64 + (m & 15)
                         + 16 * (((b & 1) << 1) | hh);
            stg16(hbuf + (size_t)((t + 1) & 1) * (BATCH * HDIM) + dst16 * 8, v);
            VMW(0);        // this wave's stores at the coherence point
            if ((tid & 63) == 0)
                stflag(&bar[(b * 2 + w) * 32], (unsigned)(t + 1));
        }

        // ---- out stores + gx prefetch, then FULL drain so the next poll
        //      loop has zero outstanding vmem (drain hides under producers)
#pragma unroll
        for (int r = 0; r < 4; ++r)
            out[((size_t)t * BATCH + mg * 4 + r) * HDIM + col] = hv[r];
        {
            const float* gp = gx + (size_t)(t + 1) * BATCH * GDIM;
#pragma unroll
            for (int r = 0; r < 4; ++r)
#pragma unroll
                for (int g = 0; g < 4; ++g)
                    gxv[r][g] = gp[(size_t)(mg * 4 + r) * GDIM + g * HDIM + col];
        }
        VMW(0);
    }
}

// ---------------------------------------------------------------------------
extern "C" void kernel_launch(void* const* d_in, const int* in_sizes, int n_in,
                              void* d_out, int out_size, void* d_ws, size_t ws_size,
                              hipStream_t stream) {
    const float* X  = (const float*)d_in[0];
    const float* h0 = (const float*)d_in[1];
    const float* c0 = (const float*)d_in[2];
    const float* Wx = (const float*)d_in[3];
    const float* Wh = (const float*)d_in[4];
    const float* bx = (const float*)d_in[5];
    const float* bh = (const float*)d_in[6];
    float* out = (float*)d_out;

    char* ws = (char*)d_ws;
    float* gx = (float*)ws;                                   // 512 MB fp32
    size_t gx_bytes = (size_t)T_STEPS * BATCH * GDIM * 4;
    unsigned short* hbuf = (unsigned short*)(ws + gx_bytes);  // 2 x 128 KB swizzled bf16
    size_t hbuf_bytes = (size_t)2 * BATCH * HDIM * 2;
    unsigned* bar = (unsigned*)(ws + gx_bytes + hbuf_bytes);  // 128 flags, 128B apart

    hipMemsetAsync(bar, 0, 128 * 32 * sizeof(unsigned), stream);
    k_h0_swz<<<dim3(32), dim3(256), 0, stream>>>(h0, hbuf);
    k_gx_gemm<<<dim3(8192), dim3(256), 0, stream>>>(X, Wx, bx, bh, gx);
    k_lstm<<<dim3(LSTM_BLOCKS), dim3(256), 0, stream>>>(gx, Wh, c0, out, hbuf, bar);
}

// Round 9
// 2619.422 us; speedup vs baseline: 1.0839x; 1.0839x over previous
//
#include <hip/hip_runtime.h>
#include <hip/hip_bf16.h>

// Problem constants
#define T_STEPS 512
#define BATCH   64
#define IDIM    1024
#define HDIM    1024
#define GDIM    4096   // 4*HDIM
#define UPB     16     // hidden units per recurrence block
#define LSTM_BLOCKS 64 // HDIM / UPB

typedef __attribute__((ext_vector_type(8))) short short8;
typedef __attribute__((ext_vector_type(8))) unsigned short ushort8;
typedef __attribute__((ext_vector_type(4))) float f32x4;

typedef __attribute__((address_space(1))) const unsigned int gas_uint;
typedef __attribute__((address_space(3))) unsigned int las_uint;

static __device__ __forceinline__ unsigned short f2bf(float f) {
    union { float f; unsigned u; } x; x.f = f;
    unsigned r = x.u + 0x7fffu + ((x.u >> 16) & 1u);  // round-to-nearest-even
    return (unsigned short)(r >> 16);
}

static __device__ __forceinline__ short8 pack8(const float* p) {
    float4 v0 = *reinterpret_cast<const float4*>(p);
    float4 v1 = *reinterpret_cast<const float4*>(p + 4);
    short8 t;
    t[0]=(short)f2bf(v0.x); t[1]=(short)f2bf(v0.y);
    t[2]=(short)f2bf(v0.z); t[3]=(short)f2bf(v0.w);
    t[4]=(short)f2bf(v1.x); t[5]=(short)f2bf(v1.y);
    t[6]=(short)f2bf(v1.z); t[7]=(short)f2bf(v1.w);
    return t;
}

// 16B coherent-bypass load/store (skip L1/L2; MALL coherence point).
static __device__ __forceinline__ short8 ldg16(const unsigned short* p) {
    short8 d;
    asm volatile("global_load_dwordx4 %0, %1, off sc0 sc1" : "=v"(d) : "v"(p));
    return d;
}
static __device__ __forceinline__ void stg16(unsigned short* p, ushort8 v) {
    asm volatile("global_store_dwordx4 %0, %1, off sc0 sc1"
                 :: "v"(p), "v"(v) : "memory");
}

// counted vmcnt wait + scheduler fence (keeps MFMAs from hoisting above it)
#define VMW(n) do { asm volatile("s_waitcnt vmcnt(" #n ")"); \
                    __builtin_amdgcn_sched_barrier(0); } while (0)

// fast activations: v_exp_f32 computes 2^x; v_rcp_f32 ~1ULP
static __device__ __forceinline__ float fexp2(float x) {
    float r; asm("v_exp_f32 %0, %1" : "=v"(r) : "v"(x)); return r;
}
static __device__ __forceinline__ float frcp(float x) {
    float r; asm("v_rcp_f32 %0, %1" : "=v"(r) : "v"(x)); return r;
}
static __device__ __forceinline__ float fsigmoid(float x) {
    return frcp(1.f + fexp2(-1.4426950408889634f * x));
}
static __device__ __forceinline__ float ftanh(float x) {
    return 2.f * frcp(1.f + fexp2(-2.8853900817779268f * x)) - 1.f;
}

// ---------------------------------------------------------------------------
// Kernel C: fp32 -> bf16 pre-cast (grid-stride, 8 elems/thread/iter)
// ---------------------------------------------------------------------------
__global__ __launch_bounds__(256) void k_cast_bf16(
        const float* __restrict__ src, unsigned short* __restrict__ dst, int n8) {
    int stride = gridDim.x * 256;
    for (int i = blockIdx.x * 256 + threadIdx.x; i < n8; i += stride) {
        const float* p = src + (size_t)i * 8;
        float4 a = *reinterpret_cast<const float4*>(p);
        float4 b = *reinterpret_cast<const float4*>(p + 4);
        ushort8 v;
        v[0]=f2bf(a.x); v[1]=f2bf(a.y); v[2]=f2bf(a.z); v[3]=f2bf(a.w);
        v[4]=f2bf(b.x); v[5]=f2bf(b.y); v[6]=f2bf(b.z); v[7]=f2bf(b.w);
        *reinterpret_cast<ushort8*>(dst + (size_t)i * 8) = v;
    }
}

// ---------------------------------------------------------------------------
// Kernel 0: h0 (fp32 [B,H]) -> swizzled bf16 buffer 0.
// 16B chunk index (Rtile*32 + s)*64 + lane holds
//   h[Rtile*16 + (lane&15)][s*32 + (lane>>4)*8 .. +8)
// ---------------------------------------------------------------------------
__global__ void k_h0_swz(const float* __restrict__ h0,
                         unsigned short* __restrict__ hbuf0) {
    int i = blockIdx.x * 256 + threadIdx.x;   // 8192 threads: 64 rows x 128 chunks
    int m  = i >> 7;
    int hh = i & 127;                         // u = hh*8
    const float* src = h0 + (size_t)m * HDIM + hh * 8;
    float4 a = *reinterpret_cast<const float4*>(src);
    float4 c = *reinterpret_cast<const float4*>(src + 4);
    ushort8 v;
    v[0]=f2bf(a.x); v[1]=f2bf(a.y); v[2]=f2bf(a.z); v[3]=f2bf(a.w);
    v[4]=f2bf(c.x); v[5]=f2bf(c.y); v[6]=f2bf(c.z); v[7]=f2bf(c.w);
    size_t dst16 = ((size_t)(m >> 4) * 32 + (hh >> 2)) * 64 + (m & 15) + 16 * (hh & 3);
    *reinterpret_cast<ushort8*>(hbuf0 + dst16 * 8) = v;  // kernel-end flush -> MALL
}

// ---------------------------------------------------------------------------
// Kernel 1 (rebuilt): gx = Xb @ Wb^T + b_x + b_h, bf16 inputs, fp32 out.
// 128x128 tile, BK=64, 4 waves x 64x64. global_load_lds 16B staging with
// src-side XOR swizzle (T2): LDS[row][c] holds global k-byte c ^ ((row&7)<<4),
// ds_read applies the same XOR -> conflict-free b128 reads.
// XCD swizzle: nt-major strips so each XCD keeps 4 B-panels (1MB) L2-resident.
// ---------------------------------------------------------------------------
__global__ __launch_bounds__(256) void k_gx_gemm2(
        const unsigned short* __restrict__ Xb, const unsigned short* __restrict__ Wb,
        const float* __restrict__ bx, const float* __restrict__ bh,
        float* __restrict__ gx) {
    __shared__ __align__(16) unsigned short As[128 * 64];  // 16 KB
    __shared__ __align__(16) unsigned short Bs[128 * 64];  // 16 KB

    const int bid  = blockIdx.x;                 // 8192
    const int vbid = (bid & 7) * 1024 + (bid >> 3);
    const int nt   = vbid >> 8;                  // 0..31  (4 per XCD strip)
    const int mt   = vbid & 255;                 // 0..255

    const int tid  = threadIdx.x;
    const int lane = tid & 63;
    const int w    = tid >> 6;
    const int l15  = lane & 15;
    const int wm   = (w >> 1) * 64;
    const int wn   = (w & 1) * 64;

    // staging source address: lane covers row r8 = lane>>3 (of 8-row issue),
    // byte-in-row csrc = ((lane&7) ^ (lane>>3)) * 16  (pre-applied swizzle)
    const int r8   = lane >> 3;
    const int csrc = (((lane & 7) ^ r8) << 4);

    const char* Xsrc[4]; const char* Wsrc[4];
#pragma unroll
    for (int i = 0; i < 4; ++i) {
        int row = w * 32 + i * 8 + r8;
        Xsrc[i] = (const char*)Xb + ((size_t)(mt * 128 + row) * IDIM) * 2 + csrc;
        Wsrc[i] = (const char*)Wb + ((size_t)(nt * 128 + row) * IDIM) * 2 + csrc;
    }

    f32x4 acc[4][4] = {};

    for (int k0 = 0; k0 < IDIM; k0 += 64) {
        __syncthreads();   // previous step's fragment reads done
#pragma unroll
        for (int i = 0; i < 4; ++i) {
            __builtin_amdgcn_global_load_lds(
                (gas_uint*)(Xsrc[i] + k0 * 2),
                (las_uint*)(As + (w * 32 + i * 8) * 64), 16, 0, 0);
            __builtin_amdgcn_global_load_lds(
                (gas_uint*)(Wsrc[i] + k0 * 2),
                (las_uint*)(Bs + (w * 32 + i * 8) * 64), 16, 0, 0);
        }
        asm volatile("s_waitcnt vmcnt(0)");
        __syncthreads();   // tile staged

        short8 af[2][4], bf_[2][4];
#pragma unroll
        for (int ks = 0; ks < 2; ++ks) {
            const int cl = ks * 64 + ((lane >> 4) << 4);   // logical byte 0..127
#pragma unroll
            for (int i = 0; i < 4; ++i) {
                const int ra = wm + i * 16 + l15;
                af[ks][i] = *reinterpret_cast<const short8*>(
                    (const char*)As + ra * 128 + (cl ^ ((ra & 7) << 4)));
                const int rb = wn + i * 16 + l15;
                bf_[ks][i] = *reinterpret_cast<const short8*>(
                    (const char*)Bs + rb * 128 + (cl ^ ((rb & 7) << 4)));
            }
        }
#pragma unroll
        for (int ks = 0; ks < 2; ++ks)
#pragma unroll
            for (int i = 0; i < 4; ++i)
#pragma unroll
                for (int j = 0; j < 4; ++j)
                    acc[i][j] = __builtin_amdgcn_mfma_f32_16x16x32_bf16(
                                    af[ks][i], bf_[ks][j], acc[i][j], 0, 0, 0);
    }

    // epilogue: += (b_x + b_h), write fp32 gx
#pragma unroll
    for (int j = 0; j < 4; ++j) {
        int n = nt * 128 + wn + j * 16 + l15;
        float bb = bx[n] + bh[n];
#pragma unroll
        for (int i = 0; i < 4; ++i) {
            int mbase = mt * 128 + wm + i * 16 + (lane >> 4) * 4;
#pragma unroll
            for (int r = 0; r < 4; ++r)
                gx[(size_t)(mbase + r) * GDIM + n] = acc[i][j][r] + bb;
        }
    }
}

// ---------------------------------------------------------------------------
// Kernel 2: persistent LSTM recurrence (r7 version — best measured).
// 64 blocks x 256 threads. Block b owns hidden units [b*16, b*16+16) = 64
// gate-cols. Wave (rh,kh): rows rh*32..+32 x 64 cols x K-half kh*512..+512;
// disjoint A chunks. W_h K-half in registers. Poll runs with ZERO outstanding
// vmem; each wave polls only its 32 producer flags (write-safety: all waves
// join at the gs sync before any h(t+1) store).
// ---------------------------------------------------------------------------
__global__ __launch_bounds__(256, 1) void k_lstm(
        const float* __restrict__ gx, const float* __restrict__ Wh,
        const float* __restrict__ cinit, float* __restrict__ out,
        unsigned short* __restrict__ hbuf, unsigned* __restrict__ bar) {
    __shared__ __align__(16) float gs[2][64][68];         // 35 KB
    __shared__ __align__(16) unsigned short hs[64][16];   // 2 KB

    const int b    = blockIdx.x;     // 64
    const int tid  = threadIdx.x;    // 256
    const int lane = tid & 63;
    const int w    = tid >> 6;       // 0..3
    const int rh   = w >> 1;         // batch-row half
    const int kh   = w & 1;          // K half
    const int l15  = lane & 15;
    const int lk8  = (lane >> 4) * 8;

    // ---- W_h (64 cols x K-half) -> registers. breg[cg*16+ks]:
    //      col = cg*16 + l15 (gate cg, unit l15), k = kh*512 + ks*32 + lk8
    short8 breg[64];
#pragma unroll
    for (int cg = 0; cg < 4; ++cg) {
        const float* wb = Wh + ((size_t)(cg * HDIM + b * UPB + l15)) * HDIM
                        + kh * 512 + lk8;
#pragma unroll
        for (int ks = 0; ks < 16; ++ks)
            breg[cg * 16 + ks] = pack8(wb + ks * 32);
    }

    // ---- per-thread gate ownership: unit u, batch rows mg*4..mg*4+3
    const int u   = tid & 15;
    const int mg  = tid >> 4;        // 0..15
    const int col = b * UPB + u;     // global hidden index

    float c_reg[4];
#pragma unroll
    for (int r = 0; r < 4; ++r)
        c_reg[r] = cinit[(size_t)(mg * 4 + r) * HDIM + col];

    // gx for t=0
    float gxv[4][4];
#pragma unroll
    for (int r = 0; r < 4; ++r)
#pragma unroll
        for (int g = 0; g < 4; ++g)
            gxv[r][g] = gx[(size_t)(mg * 4 + r) * GDIM + g * HDIM + col];

    __syncthreads();   // also drains the gxv/c_reg loads: t=0 poll is clean

    // this wave's flag subset: producers [kh*32, kh*32+32), 32 lines
    const unsigned* fb = &bar[(kh * 32 + (lane & 31)) * 32];

    for (int t = 0; t < T_STEPS; ++t) {
        // ---- poll (clean: no outstanding vmem when we get here)
        {
            unsigned v = __hip_atomic_load(fb, __ATOMIC_RELAXED,
                                           __HIP_MEMORY_SCOPE_AGENT);
            while (!__all((int)(v >= (unsigned)t))) {
                __builtin_amdgcn_s_sleep(2);
                v = __hip_atomic_load(fb, __ATOMIC_RELAXED,
                                      __HIP_MEMORY_SCOPE_AGENT);
            }
        }
        asm volatile("" ::: "memory");   // keep bypass loads below the poll

        // ---- A stream: chunks (rh*2+rp)*32 + kh*16 + ks, contiguous 1KB each
        const unsigned short* hA2 = hbuf + (size_t)(t & 1) * (BATCH * HDIM)
                                  + ((size_t)rh * 64 + kh * 16) * 512 + lane * 8;
        short8 st[24];
#define SLOT(i) ((i) < 24 ? (i) : (i) - 24)
#define ISSK(ks) do { \
        st[SLOT((ks) * 2)]     = ldg16(hA2 + (ks) * 512);          \
        st[SLOT((ks) * 2 + 1)] = ldg16(hA2 + 16384 + (ks) * 512);  \
    } while (0)
#define CONS1(ks) do { \
        short8 a0 = st[SLOT((ks) * 2)], a1 = st[SLOT((ks) * 2 + 1)]; \
        accP0 = __builtin_amdgcn_mfma_f32_16x16x32_bf16(a0, breg[(ks)],      accP0, 0, 0, 0); \
        accP1 = __builtin_amdgcn_mfma_f32_16x16x32_bf16(a0, breg[16 + (ks)], accP1, 0, 0, 0); \
        accP2 = __builtin_amdgcn_mfma_f32_16x16x32_bf16(a0, breg[32 + (ks)], accP2, 0, 0, 0); \
        accP3 = __builtin_amdgcn_mfma_f32_16x16x32_bf16(a0, breg[48 + (ks)], accP3, 0, 0, 0); \
        accQ0 = __builtin_amdgcn_mfma_f32_16x16x32_bf16(a1, breg[(ks)],      accQ0, 0, 0, 0); \
        accQ1 = __builtin_amdgcn_mfma_f32_16x16x32_bf16(a1, breg[16 + (ks)], accQ1, 0, 0, 0); \
        accQ2 = __builtin_amdgcn_mfma_f32_16x16x32_bf16(a1, breg[32 + (ks)], accQ2, 0, 0, 0); \
        accQ3 = __builtin_amdgcn_mfma_f32_16x16x32_bf16(a1, breg[48 + (ks)], accQ3, 0, 0, 0); \
    } while (0)

        f32x4 accP0 = {}, accP1 = {}, accP2 = {}, accP3 = {};
        f32x4 accQ0 = {}, accQ1 = {}, accQ2 = {}, accQ3 = {};
        ISSK(0); ISSK(1); ISSK(2);  ISSK(3);  ISSK(4);  ISSK(5);
        ISSK(6); ISSK(7); ISSK(8);  ISSK(9);  ISSK(10); ISSK(11);   // 24 in flight
        VMW(16); CONS1(0);  CONS1(1);  CONS1(2);  CONS1(3);
        ISSK(12); ISSK(13); ISSK(14); ISSK(15);
        VMW(16); CONS1(4);  CONS1(5);  CONS1(6);  CONS1(7);
        VMW(8);  CONS1(8);  CONS1(9);  CONS1(10); CONS1(11);
        VMW(0);  CONS1(12); CONS1(13); CONS1(14); CONS1(15);
#undef SLOT
#undef ISSK
#undef CONS1

        // ---- partials -> gs[kh]
        {
            const int gr = rh * 32 + (lane >> 4) * 4;
#pragma unroll
            for (int r = 0; r < 4; ++r) {
                gs[kh][gr + r][l15]           = accP0[r];
                gs[kh][gr + r][16 + l15]      = accP1[r];
                gs[kh][gr + r][32 + l15]      = accP2[r];
                gs[kh][gr + r][48 + l15]      = accP3[r];
                gs[kh][gr + 16 + r][l15]      = accQ0[r];
                gs[kh][gr + 16 + r][16 + l15] = accQ1[r];
                gs[kh][gr + 16 + r][32 + l15] = accQ2[r];
                gs[kh][gr + 16 + r][48 + l15] = accQ3[r];
            }
        }
        __syncthreads();   // joins both kh halves: all 64 flags verified >= t

        // ---- gates + state update (all 256 threads, 4 batch rows each)
        float hv[4];
#pragma unroll
        for (int r = 0; r < 4; ++r) {
            const int m = mg * 4 + r;
            float xi = gxv[r][0] + gs[0][m][u]      + gs[1][m][u];
            float xf = gxv[r][1] + gs[0][m][16 + u] + gs[1][m][16 + u];
            float xo = gxv[r][2] + gs[0][m][32 + u] + gs[1][m][32 + u];
            float xn = gxv[r][3] + gs[0][m][48 + u] + gs[1][m][48 + u];
            float ig = fsigmoid(xi);
            float fg = fsigmoid(xf);
            float og = fsigmoid(xo);
            float ng = ftanh(xn);
            c_reg[r] = fg * c_reg[r] + ig * ng;
            float h = og * ftanh(c_reg[r]);
            hv[r] = h;
            hs[m][u] = f2bf(h);
        }

        if (t == T_STEPS - 1) {
            size_t fin = (size_t)T_STEPS * BATCH * HDIM;
#pragma unroll
            for (int r = 0; r < 4; ++r) {
                const int m = mg * 4 + r;
                out[((size_t)t * BATCH + m) * HDIM + col] = hv[r];
                out[fin + (size_t)m * HDIM + col] = hv[r];                           // h_fin
                out[fin + (size_t)BATCH * HDIM + (size_t)m * HDIM + col] = c_reg[r]; // c_fin
            }
            break;
        }

        __syncthreads();   // hs complete

        // ---- packed swizzled h store -> MALL (128 threads x 16B)
        if (tid < 128) {
            const int m  = tid >> 1;
            const int hh = tid & 1;
            ushort8 v = *reinterpret_cast<const ushort8*>(&hs[m][hh * 8]);
            size_t dst16 = ((size_t)(m >> 4) * 32 + (b >> 1)) * 64 + (m & 15)
                         + 16 * (((b & 1) << 1) | hh);
            stg16(hbuf + (size_t)((t + 1) & 1) * (BATCH * HDIM) + dst16 * 8, v);
        }
        // __syncthreads implies per-wave s_waitcnt vmcnt(0): h stores of ALL
        // storing waves are at the coherence point before the flag goes up.
        __syncthreads();
        if (tid == 0)
            __hip_atomic_store(&bar[b * 32], (unsigned)(t + 1),
                               __ATOMIC_RELAXED, __HIP_MEMORY_SCOPE_AGENT);

        // ---- out stores + gx prefetch, then FULL drain so the next poll
        //      loop has zero outstanding vmem (drain hides under producers)
#pragma unroll
        for (int r = 0; r < 4; ++r)
            out[((size_t)t * BATCH + mg * 4 + r) * HDIM + col] = hv[r];
        {
            const float* gp = gx + (size_t)(t + 1) * BATCH * GDIM;
#pragma unroll
            for (int r = 0; r < 4; ++r)
#pragma unroll
                for (int g = 0; g < 4; ++g)
                    gxv[r][g] = gp[(size_t)(mg * 4 + r) * GDIM + g * HDIM + col];
        }
        VMW(0);
    }
}

// ---------------------------------------------------------------------------
extern "C" void kernel_launch(void* const* d_in, const int* in_sizes, int n_in,
                              void* d_out, int out_size, void* d_ws, size_t ws_size,
                              hipStream_t stream) {
    const float* X  = (const float*)d_in[0];
    const float* h0 = (const float*)d_in[1];
    const float* c0 = (const float*)d_in[2];
    const float* Wx = (const float*)d_in[3];
    const float* Wh = (const float*)d_in[4];
    const float* bx = (const float*)d_in[5];
    const float* bh = (const float*)d_in[6];
    float* out = (float*)d_out;

    char* ws = (char*)d_ws;
    float* gx = (float*)ws;                                   // 512 MB fp32
    size_t gx_bytes = (size_t)T_STEPS * BATCH * GDIM * 4;
    unsigned short* hbuf = (unsigned short*)(ws + gx_bytes);  // 2 x 128 KB swizzled bf16
    size_t hbuf_bytes = (size_t)2 * BATCH * HDIM * 2;
    unsigned* bar = (unsigned*)(ws + gx_bytes + hbuf_bytes);  // 64 flags, 128B apart

    // bf16 pre-cast scratch lives in d_out (75 MB < 128.5 MB); k_lstm fully
    // overwrites d_out afterwards, so the final contents are correct.
    unsigned short* Xb  = (unsigned short*)d_out;             // 33.5M elems
    unsigned short* Wxb = Xb + (size_t)T_STEPS * BATCH * IDIM;// 4.2M elems

    hipMemsetAsync(bar, 0, LSTM_BLOCKS * 32 * sizeof(unsigned), stream);
    k_cast_bf16<<<dim3(2048), dim3(256), 0, stream>>>(
        X, Xb, (int)((size_t)T_STEPS * BATCH * IDIM / 8));
    k_cast_bf16<<<dim3(512), dim3(256), 0, stream>>>(
        Wx, Wxb, (int)((size_t)GDIM * IDIM / 8));
    k_h0_swz<<<dim3(32), dim3(256), 0, stream>>>(h0, hbuf);
    k_gx_gemm2<<<dim3(8192), dim3(256), 0, stream>>>(Xb, Wxb, bx, bh, gx);
    k_lstm<<<dim3(LSTM_BLOCKS), dim3(256), 0, stream>>>(gx, Wh, c0, out, hbuf, bar);
}

// Round 10
// 2501.468 us; speedup vs baseline: 1.1350x; 1.0472x over previous
//
#include <hip/hip_runtime.h>
#include <hip/hip_bf16.h>

// Problem constants
#define T_STEPS 512
#define BATCH   64
#define IDIM    1024
#define HDIM    1024
#define GDIM    4096   // 4*HDIM
#define UPB     16     // hidden units per recurrence block
#define LSTM_BLOCKS 64 // HDIM / UPB

typedef __attribute__((ext_vector_type(8))) short short8;
typedef __attribute__((ext_vector_type(8))) unsigned short ushort8;
typedef __attribute__((ext_vector_type(4))) float f32x4;

typedef __attribute__((address_space(1))) const unsigned int gas_uint;
typedef __attribute__((address_space(3))) unsigned int las_uint;

static __device__ __forceinline__ unsigned short f2bf(float f) {
    union { float f; unsigned u; } x; x.f = f;
    unsigned r = x.u + 0x7fffu + ((x.u >> 16) & 1u);  // round-to-nearest-even
    return (unsigned short)(r >> 16);
}

static __device__ __forceinline__ short8 pack8(const float* p) {
    float4 v0 = *reinterpret_cast<const float4*>(p);
    float4 v1 = *reinterpret_cast<const float4*>(p + 4);
    short8 t;
    t[0]=(short)f2bf(v0.x); t[1]=(short)f2bf(v0.y);
    t[2]=(short)f2bf(v0.z); t[3]=(short)f2bf(v0.w);
    t[4]=(short)f2bf(v1.x); t[5]=(short)f2bf(v1.y);
    t[6]=(short)f2bf(v1.z); t[7]=(short)f2bf(v1.w);
    return t;
}

// 16B coherent-bypass load/store (skip L1/L2; MALL coherence point).
static __device__ __forceinline__ short8 ldg16(const unsigned short* p) {
    short8 d;
    asm volatile("global_load_dwordx4 %0, %1, off sc0 sc1" : "=v"(d) : "v"(p));
    return d;
}
static __device__ __forceinline__ void stg16(unsigned short* p, ushort8 v) {
    asm volatile("global_store_dwordx4 %0, %1, off sc0 sc1"
                 :: "v"(p), "v"(v) : "memory");
}

// counted vmcnt wait + scheduler fence (keeps MFMAs from hoisting above it)
#define VMW(n) do { asm volatile("s_waitcnt vmcnt(" #n ")"); \
                    __builtin_amdgcn_sched_barrier(0); } while (0)

// fast activations: v_exp_f32 computes 2^x; v_rcp_f32 ~1ULP
static __device__ __forceinline__ float fexp2(float x) {
    float r; asm("v_exp_f32 %0, %1" : "=v"(r) : "v"(x)); return r;
}
static __device__ __forceinline__ float frcp(float x) {
    float r; asm("v_rcp_f32 %0, %1" : "=v"(r) : "v"(x)); return r;
}
static __device__ __forceinline__ float fsigmoid(float x) {
    return frcp(1.f + fexp2(-1.4426950408889634f * x));
}
static __device__ __forceinline__ float ftanh(float x) {
    return 2.f * frcp(1.f + fexp2(-2.8853900817779268f * x)) - 1.f;
}

// ---------------------------------------------------------------------------
// Kernel C: fp32 -> bf16 pre-cast (grid-stride, 8 elems/thread/iter)
// ---------------------------------------------------------------------------
__global__ __launch_bounds__(256) void k_cast_bf16(
        const float* __restrict__ src, unsigned short* __restrict__ dst, int n8) {
    int stride = gridDim.x * 256;
    for (int i = blockIdx.x * 256 + threadIdx.x; i < n8; i += stride) {
        const float* p = src + (size_t)i * 8;
        float4 a = *reinterpret_cast<const float4*>(p);
        float4 b = *reinterpret_cast<const float4*>(p + 4);
        ushort8 v;
        v[0]=f2bf(a.x); v[1]=f2bf(a.y); v[2]=f2bf(a.z); v[3]=f2bf(a.w);
        v[4]=f2bf(b.x); v[5]=f2bf(b.y); v[6]=f2bf(b.z); v[7]=f2bf(b.w);
        *reinterpret_cast<ushort8*>(dst + (size_t)i * 8) = v;
    }
}

// ---------------------------------------------------------------------------
// Kernel 0: h0 (fp32 [B,H]) -> swizzled bf16 buffer 0.
// 16B chunk index (Rtile*32 + s)*64 + lane holds
//   h[Rtile*16 + (lane&15)][s*32 + (lane>>4)*8 .. +8)
// ---------------------------------------------------------------------------
__global__ void k_h0_swz(const float* __restrict__ h0,
                         unsigned short* __restrict__ hbuf0) {
    int i = blockIdx.x * 256 + threadIdx.x;   // 8192 threads: 64 rows x 128 chunks
    int m  = i >> 7;
    int hh = i & 127;                         // u = hh*8
    const float* src = h0 + (size_t)m * HDIM + hh * 8;
    float4 a = *reinterpret_cast<const float4*>(src);
    float4 c = *reinterpret_cast<const float4*>(src + 4);
    ushort8 v;
    v[0]=f2bf(a.x); v[1]=f2bf(a.y); v[2]=f2bf(a.z); v[3]=f2bf(a.w);
    v[4]=f2bf(c.x); v[5]=f2bf(c.y); v[6]=f2bf(c.z); v[7]=f2bf(c.w);
    size_t dst16 = ((size_t)(m >> 4) * 32 + (hh >> 2)) * 64 + (m & 15) + 16 * (hh & 3);
    *reinterpret_cast<ushort8*>(hbuf0 + dst16 * 8) = v;  // kernel-end flush -> MALL
}

// ---------------------------------------------------------------------------
// Kernel 1: gx = Xb @ Wb^T + b_x + b_h, bf16 inputs, fp32 out (r9 version).
// 128x128 tile, BK=64, 4 waves x 64x64. global_load_lds 16B staging with
// src-side XOR swizzle; XCD-swizzled nt-strips.
// ---------------------------------------------------------------------------
__global__ __launch_bounds__(256) void k_gx_gemm2(
        const unsigned short* __restrict__ Xb, const unsigned short* __restrict__ Wb,
        const float* __restrict__ bx, const float* __restrict__ bh,
        float* __restrict__ gx) {
    __shared__ __align__(16) unsigned short As[128 * 64];  // 16 KB
    __shared__ __align__(16) unsigned short Bs[128 * 64];  // 16 KB

    const int bid  = blockIdx.x;                 // 8192
    const int vbid = (bid & 7) * 1024 + (bid >> 3);
    const int nt   = vbid >> 8;                  // 0..31  (4 per XCD strip)
    const int mt   = vbid & 255;                 // 0..255

    const int tid  = threadIdx.x;
    const int lane = tid & 63;
    const int w    = tid >> 6;
    const int l15  = lane & 15;
    const int wm   = (w >> 1) * 64;
    const int wn   = (w & 1) * 64;

    const int r8   = lane >> 3;
    const int csrc = (((lane & 7) ^ r8) << 4);

    const char* Xsrc[4]; const char* Wsrc[4];
#pragma unroll
    for (int i = 0; i < 4; ++i) {
        int row = w * 32 + i * 8 + r8;
        Xsrc[i] = (const char*)Xb + ((size_t)(mt * 128 + row) * IDIM) * 2 + csrc;
        Wsrc[i] = (const char*)Wb + ((size_t)(nt * 128 + row) * IDIM) * 2 + csrc;
    }

    f32x4 acc[4][4] = {};

    for (int k0 = 0; k0 < IDIM; k0 += 64) {
        __syncthreads();   // previous step's fragment reads done
#pragma unroll
        for (int i = 0; i < 4; ++i) {
            __builtin_amdgcn_global_load_lds(
                (gas_uint*)(Xsrc[i] + k0 * 2),
                (las_uint*)(As + (w * 32 + i * 8) * 64), 16, 0, 0);
            __builtin_amdgcn_global_load_lds(
                (gas_uint*)(Wsrc[i] + k0 * 2),
                (las_uint*)(Bs + (w * 32 + i * 8) * 64), 16, 0, 0);
        }
        asm volatile("s_waitcnt vmcnt(0)");
        __syncthreads();   // tile staged

        short8 af[2][4], bf_[2][4];
#pragma unroll
        for (int ks = 0; ks < 2; ++ks) {
            const int cl = ks * 64 + ((lane >> 4) << 4);   // logical byte 0..127
#pragma unroll
            for (int i = 0; i < 4; ++i) {
                const int ra = wm + i * 16 + l15;
                af[ks][i] = *reinterpret_cast<const short8*>(
                    (const char*)As + ra * 128 + (cl ^ ((ra & 7) << 4)));
                const int rb = wn + i * 16 + l15;
                bf_[ks][i] = *reinterpret_cast<const short8*>(
                    (const char*)Bs + rb * 128 + (cl ^ ((rb & 7) << 4)));
            }
        }
#pragma unroll
        for (int ks = 0; ks < 2; ++ks)
#pragma unroll
            for (int i = 0; i < 4; ++i)
#pragma unroll
                for (int j = 0; j < 4; ++j)
                    acc[i][j] = __builtin_amdgcn_mfma_f32_16x16x32_bf16(
                                    af[ks][i], bf_[ks][j], acc[i][j], 0, 0, 0);
    }

    // epilogue: += (b_x + b_h), write fp32 gx
#pragma unroll
    for (int j = 0; j < 4; ++j) {
        int n = nt * 128 + wn + j * 16 + l15;
        float bb = bx[n] + bh[n];
#pragma unroll
        for (int i = 0; i < 4; ++i) {
            int mbase = mt * 128 + wm + i * 16 + (lane >> 4) * 4;
#pragma unroll
            for (int r = 0; r < 4; ++r)
                gx[(size_t)(mbase + r) * GDIM + n] = acc[i][j][r] + bb;
        }
    }
}

// ---------------------------------------------------------------------------
// Kernel 2: persistent LSTM recurrence.
// 64 blocks x 256 threads. Block b owns hidden units [b*16, b*16+16) = 64
// gate-cols. Wave (rh,kh): rows rh*32..+32 x 64 cols x K-half kh*512..+512;
// disjoint A chunks. W_h K-half in registers.
// Round 10: gate/tail thread remap -> thread = (row m = tid>>2, unit quad
// q = tid&3). All tail memory ops vector-width: gx prefetch 4x float4 (was
// 16 scalar), out 1x 16B (was 4 scalar), gs 8x float4 LDS reads, hs 1x 8B.
// Bit-identical arithmetic; pure op-count reduction on the drained window.
// ---------------------------------------------------------------------------
__global__ __launch_bounds__(256, 1) void k_lstm(
        const float* __restrict__ gx, const float* __restrict__ Wh,
        const float* __restrict__ cinit, float* __restrict__ out,
        unsigned short* __restrict__ hbuf, unsigned* __restrict__ bar) {
    __shared__ __align__(16) float gs[2][64][68];         // 35 KB (68*4B = 17x16B)
    __shared__ __align__(16) unsigned short hs[64][16];   // 2 KB

    const int b    = blockIdx.x;     // 64
    const int tid  = threadIdx.x;    // 256
    const int lane = tid & 63;
    const int w    = tid >> 6;       // 0..3
    const int rh   = w >> 1;         // batch-row half
    const int kh   = w & 1;          // K half
    const int l15  = lane & 15;
    const int lk8  = (lane >> 4) * 8;

    // ---- W_h (64 cols x K-half) -> registers. breg[cg*16+ks]:
    //      col = cg*16 + l15 (gate cg, unit l15), k = kh*512 + ks*32 + lk8
    short8 breg[64];
#pragma unroll
    for (int cg = 0; cg < 4; ++cg) {
        const float* wb = Wh + ((size_t)(cg * HDIM + b * UPB + l15)) * HDIM
                        + kh * 512 + lk8;
#pragma unroll
        for (int ks = 0; ks < 16; ++ks)
            breg[cg * 16 + ks] = pack8(wb + ks * 32);
    }

    // ---- per-thread gate ownership: row m, unit quad q (units u0..u0+3)
    const int m    = tid >> 2;       // 0..63
    const int q    = tid & 3;
    const int u0   = q * 4;
    const int col0 = b * UPB + u0;   // global col of first unit (16B aligned)

    float4 c4 = *reinterpret_cast<const float4*>(&cinit[(size_t)m * HDIM + col0]);

    // gx for t=0: one float4 per gate
    float4 gxv[4];
#pragma unroll
    for (int g = 0; g < 4; ++g)
        gxv[g] = *reinterpret_cast<const float4*>(
            &gx[(size_t)m * GDIM + g * HDIM + col0]);

    __syncthreads();   // also drains the gxv/c4 loads: t=0 poll is clean

    // this wave's flag subset: producers [kh*32, kh*32+32), 32 lines
    const unsigned* fb = &bar[(kh * 32 + (lane & 31)) * 32];

    for (int t = 0; t < T_STEPS; ++t) {
        // ---- poll (clean: no outstanding vmem when we get here)
        {
            unsigned v = __hip_atomic_load(fb, __ATOMIC_RELAXED,
                                           __HIP_MEMORY_SCOPE_AGENT);
            while (!__all((int)(v >= (unsigned)t))) {
                __builtin_amdgcn_s_sleep(2);
                v = __hip_atomic_load(fb, __ATOMIC_RELAXED,
                                      __HIP_MEMORY_SCOPE_AGENT);
            }
        }
        asm volatile("" ::: "memory");   // keep bypass loads below the poll

        // ---- A stream: chunks (rh*2+rp)*32 + kh*16 + ks, contiguous 1KB each
        const unsigned short* hA2 = hbuf + (size_t)(t & 1) * (BATCH * HDIM)
                                  + ((size_t)rh * 64 + kh * 16) * 512 + lane * 8;
        short8 st[24];
#define SLOT(i) ((i) < 24 ? (i) : (i) - 24)
#define ISSK(ks) do { \
        st[SLOT((ks) * 2)]     = ldg16(hA2 + (ks) * 512);          \
        st[SLOT((ks) * 2 + 1)] = ldg16(hA2 + 16384 + (ks) * 512);  \
    } while (0)
#define CONS1(ks) do { \
        short8 a0 = st[SLOT((ks) * 2)], a1 = st[SLOT((ks) * 2 + 1)]; \
        accP0 = __builtin_amdgcn_mfma_f32_16x16x32_bf16(a0, breg[(ks)],      accP0, 0, 0, 0); \
        accP1 = __builtin_amdgcn_mfma_f32_16x16x32_bf16(a0, breg[16 + (ks)], accP1, 0, 0, 0); \
        accP2 = __builtin_amdgcn_mfma_f32_16x16x32_bf16(a0, breg[32 + (ks)], accP2, 0, 0, 0); \
        accP3 = __builtin_amdgcn_mfma_f32_16x16x32_bf16(a0, breg[48 + (ks)], accP3, 0, 0, 0); \
        accQ0 = __builtin_amdgcn_mfma_f32_16x16x32_bf16(a1, breg[(ks)],      accQ0, 0, 0, 0); \
        accQ1 = __builtin_amdgcn_mfma_f32_16x16x32_bf16(a1, breg[16 + (ks)], accQ1, 0, 0, 0); \
        accQ2 = __builtin_amdgcn_mfma_f32_16x16x32_bf16(a1, breg[32 + (ks)], accQ2, 0, 0, 0); \
        accQ3 = __builtin_amdgcn_mfma_f32_16x16x32_bf16(a1, breg[48 + (ks)], accQ3, 0, 0, 0); \
    } while (0)

        f32x4 accP0 = {}, accP1 = {}, accP2 = {}, accP3 = {};
        f32x4 accQ0 = {}, accQ1 = {}, accQ2 = {}, accQ3 = {};
        ISSK(0); ISSK(1); ISSK(2);  ISSK(3);  ISSK(4);  ISSK(5);
        ISSK(6); ISSK(7); ISSK(8);  ISSK(9);  ISSK(10); ISSK(11);   // 24 in flight
        VMW(16); CONS1(0);  CONS1(1);  CONS1(2);  CONS1(3);
        ISSK(12); ISSK(13); ISSK(14); ISSK(15);
        VMW(16); CONS1(4);  CONS1(5);  CONS1(6);  CONS1(7);
        VMW(8);  CONS1(8);  CONS1(9);  CONS1(10); CONS1(11);
        VMW(0);  CONS1(12); CONS1(13); CONS1(14); CONS1(15);
#undef SLOT
#undef ISSK
#undef CONS1

        // ---- partials -> gs[kh]
        {
            const int gr = rh * 32 + (lane >> 4) * 4;
#pragma unroll
            for (int r = 0; r < 4; ++r) {
                gs[kh][gr + r][l15]           = accP0[r];
                gs[kh][gr + r][16 + l15]      = accP1[r];
                gs[kh][gr + r][32 + l15]      = accP2[r];
                gs[kh][gr + r][48 + l15]      = accP3[r];
                gs[kh][gr + 16 + r][l15]      = accQ0[r];
                gs[kh][gr + 16 + r][16 + l15] = accQ1[r];
                gs[kh][gr + 16 + r][32 + l15] = accQ2[r];
                gs[kh][gr + 16 + r][48 + l15] = accQ3[r];
            }
        }
        __syncthreads();   // joins both kh halves: all 64 flags verified >= t

        // ---- gates + state update: thread = (row m, units u0..u0+3)
        float4 hv4;
        {
            float4 s0[4], s1[4];
#pragma unroll
            for (int g = 0; g < 4; ++g) {
                s0[g] = *reinterpret_cast<const float4*>(&gs[0][m][g * 16 + u0]);
                s1[g] = *reinterpret_cast<const float4*>(&gs[1][m][g * 16 + u0]);
            }
#pragma unroll
            for (int j = 0; j < 4; ++j) {
                float xi = gxv[0][j] + s0[0][j] + s1[0][j];
                float xf = gxv[1][j] + s0[1][j] + s1[1][j];
                float xo = gxv[2][j] + s0[2][j] + s1[2][j];
                float xn = gxv[3][j] + s0[3][j] + s1[3][j];
                float ig = fsigmoid(xi);
                float fg = fsigmoid(xf);
                float og = fsigmoid(xo);
                float ng = ftanh(xn);
                c4[j] = fg * c4[j] + ig * ng;
                hv4[j] = og * ftanh(c4[j]);
            }
            // hs write: 4 adjacent bf16 = 8B
            unsigned p0 = (unsigned)f2bf(hv4.x) | ((unsigned)f2bf(hv4.y) << 16);
            unsigned p1 = (unsigned)f2bf(hv4.z) | ((unsigned)f2bf(hv4.w) << 16);
            uint2 pk; pk.x = p0; pk.y = p1;
            *reinterpret_cast<uint2*>(&hs[m][u0]) = pk;
        }

        if (t == T_STEPS - 1) {
            size_t fin = (size_t)T_STEPS * BATCH * HDIM;
            *reinterpret_cast<float4*>(
                &out[((size_t)t * BATCH + m) * HDIM + col0]) = hv4;
            *reinterpret_cast<float4*>(
                &out[fin + (size_t)m * HDIM + col0]) = hv4;                 // h_fin
            *reinterpret_cast<float4*>(
                &out[fin + (size_t)BATCH * HDIM + (size_t)m * HDIM + col0]) = c4; // c_fin
            break;
        }

        __syncthreads();   // hs complete

        // ---- packed swizzled h store -> MALL (128 threads x 16B)
        if (tid < 128) {
            const int mm = tid >> 1;
            const int hh = tid & 1;
            ushort8 v = *reinterpret_cast<const ushort8*>(&hs[mm][hh * 8]);
            size_t dst16 = ((size_t)(mm >> 4) * 32 + (b >> 1)) * 64 + (mm & 15)
                         + 16 * (((b & 1) << 1) | hh);
            stg16(hbuf + (size_t)((t + 1) & 1) * (BATCH * HDIM) + dst16 * 8, v);
        }
        // __syncthreads implies per-wave s_waitcnt vmcnt(0): h stores of ALL
        // storing waves are at the coherence point before the flag goes up.
        __syncthreads();
        if (tid == 0)
            __hip_atomic_store(&bar[b * 32], (unsigned)(t + 1),
                               __ATOMIC_RELAXED, __HIP_MEMORY_SCOPE_AGENT);

        // ---- out store (1x 16B) + gx prefetch (4x float4), then FULL drain
        //      so the next poll has zero outstanding vmem
        *reinterpret_cast<float4*>(
            &out[((size_t)t * BATCH + m) * HDIM + col0]) = hv4;
        {
            const float* gp = gx + (size_t)(t + 1) * BATCH * GDIM
                            + (size_t)m * GDIM + col0;
#pragma unroll
            for (int g = 0; g < 4; ++g)
                gxv[g] = *reinterpret_cast<const float4*>(gp + g * HDIM);
        }
        VMW(0);
    }
}

// ---------------------------------------------------------------------------
extern "C" void kernel_launch(void* const* d_in, const int* in_sizes, int n_in,
                              void* d_out, int out_size, void* d_ws, size_t ws_size,
                              hipStream_t stream) {
    const float* X  = (const float*)d_in[0];
    const float* h0 = (const float*)d_in[1];
    const float* c0 = (const float*)d_in[2];
    const float* Wx = (const float*)d_in[3];
    const float* Wh = (const float*)d_in[4];
    const float* bx = (const float*)d_in[5];
    const float* bh = (const float*)d_in[6];
    float* out = (float*)d_out;

    char* ws = (char*)d_ws;
    float* gx = (float*)ws;                                   // 512 MB fp32
    size_t gx_bytes = (size_t)T_STEPS * BATCH * GDIM * 4;
    unsigned short* hbuf = (unsigned short*)(ws + gx_bytes);  // 2 x 128 KB swizzled bf16
    size_t hbuf_bytes = (size_t)2 * BATCH * HDIM * 2;
    unsigned* bar = (unsigned*)(ws + gx_bytes + hbuf_bytes);  // 64 flags, 128B apart

    // bf16 pre-cast scratch lives in d_out (75 MB < 128.5 MB); k_lstm fully
    // overwrites d_out afterwards, so the final contents are correct.
    unsigned short* Xb  = (unsigned short*)d_out;             // 33.5M elems
    unsigned short* Wxb = Xb + (size_t)T_STEPS * BATCH * IDIM;// 4.2M elems

    hipMemsetAsync(bar, 0, LSTM_BLOCKS * 32 * sizeof(unsigned), stream);
    k_cast_bf16<<<dim3(2048), dim3(256), 0, stream>>>(
        X, Xb, (int)((size_t)T_STEPS * BATCH * IDIM / 8));
    k_cast_bf16<<<dim3(512), dim3(256), 0, stream>>>(
        Wx, Wxb, (int)((size_t)GDIM * IDIM / 8));
    k_h0_swz<<<dim3(32), dim3(256), 0, stream>>>(h0, hbuf);
    k_gx_gemm2<<<dim3(8192), dim3(256), 0, stream>>>(Xb, Wxb, bx, bh, gx);
    k_lstm<<<dim3(LSTM_BLOCKS), dim3(256), 0, stream>>>(gx, Wh, c0, out, hbuf, bar);
}

// Round 11
// 2224.961 us; speedup vs baseline: 1.2761x; 1.1243x over previous
//
#include <hip/hip_runtime.h>
#include <hip/hip_bf16.h>

// Problem constants
#define T_STEPS 512
#define BATCH   64
#define IDIM    1024
#define HDIM    1024
#define GDIM    4096   // 4*HDIM
#define UPB     16     // hidden units per recurrence block
#define NGEMM   192    // producer blocks
#define NREC    64     // consumer (recurrence) blocks
#define NTILES  8192   // (32768/128) * (4096/128)

typedef __attribute__((ext_vector_type(8))) short short8;
typedef __attribute__((ext_vector_type(8))) unsigned short ushort8;
typedef __attribute__((ext_vector_type(4))) float f32x4;

static __device__ __forceinline__ unsigned short f2bf(float f) {
    union { float f; unsigned u; } x; x.f = f;
    unsigned r = x.u + 0x7fffu + ((x.u >> 16) & 1u);  // round-to-nearest-even
    return (unsigned short)(r >> 16);
}

static __device__ __forceinline__ short8 pack8(const float* p) {
    float4 v0 = *reinterpret_cast<const float4*>(p);
    float4 v1 = *reinterpret_cast<const float4*>(p + 4);
    short8 t;
    t[0]=(short)f2bf(v0.x); t[1]=(short)f2bf(v0.y);
    t[2]=(short)f2bf(v0.z); t[3]=(short)f2bf(v0.w);
    t[4]=(short)f2bf(v1.x); t[5]=(short)f2bf(v1.y);
    t[6]=(short)f2bf(v1.z); t[7]=(short)f2bf(v1.w);
    return t;
}

// Coherent-bypass ops (skip L1/L2; MALL coherence point).
static __device__ __forceinline__ short8 ldg16(const unsigned short* p) {
    short8 d;
    asm volatile("global_load_dwordx4 %0, %1, off sc0 sc1" : "=v"(d) : "v"(p));
    return d;
}
static __device__ __forceinline__ f32x4 ldg16f(const float* p) {
    f32x4 d;
    asm volatile("global_load_dwordx4 %0, %1, off sc0 sc1" : "=v"(d) : "v"(p));
    return d;
}
static __device__ __forceinline__ void stg16(unsigned short* p, ushort8 v) {
    asm volatile("global_store_dwordx4 %0, %1, off sc0 sc1"
                 :: "v"(p), "v"(v) : "memory");
}
static __device__ __forceinline__ void stgf(float* p, float v) {
    asm volatile("global_store_dword %0, %1, off sc0 sc1"
                 :: "v"(p), "v"(v) : "memory");
}
static __device__ __forceinline__ unsigned ldflag(const unsigned* p) {
    unsigned d;
    asm volatile("global_load_dword %0, %1, off sc0 sc1" : "=v"(d) : "v"(p));
    return d;
}
static __device__ __forceinline__ void stflag(unsigned* p, unsigned v) {
    asm volatile("global_store_dword %0, %1, off sc0 sc1"
                 :: "v"(p), "v"(v) : "memory");
}

// counted vmcnt wait + scheduler fence
#define VMW(n) do { asm volatile("s_waitcnt vmcnt(" #n ")"); \
                    __builtin_amdgcn_sched_barrier(0); } while (0)

// fast activations
static __device__ __forceinline__ float fexp2(float x) {
    float r; asm("v_exp_f32 %0, %1" : "=v"(r) : "v"(x)); return r;
}
static __device__ __forceinline__ float frcp(float x) {
    float r; asm("v_rcp_f32 %0, %1" : "=v"(r) : "v"(x)); return r;
}
static __device__ __forceinline__ float fsigmoid(float x) {
    return frcp(1.f + fexp2(-1.4426950408889634f * x));
}
static __device__ __forceinline__ float ftanh(float x) {
    return 2.f * frcp(1.f + fexp2(-2.8853900817779268f * x)) - 1.f;
}

// ---------------------------------------------------------------------------
// Kernel 0: h0 (fp32 [B,H]) -> swizzled bf16 buffer 0.
// ---------------------------------------------------------------------------
__global__ void k_h0_swz(const float* __restrict__ h0,
                         unsigned short* __restrict__ hbuf0) {
    int i = blockIdx.x * 256 + threadIdx.x;   // 8192 threads: 64 rows x 128 chunks
    int m  = i >> 7;
    int hh = i & 127;                         // u = hh*8
    const float* src = h0 + (size_t)m * HDIM + hh * 8;
    float4 a = *reinterpret_cast<const float4*>(src);
    float4 c = *reinterpret_cast<const float4*>(src + 4);
    ushort8 v;
    v[0]=f2bf(a.x); v[1]=f2bf(a.y); v[2]=f2bf(a.z); v[3]=f2bf(a.w);
    v[4]=f2bf(c.x); v[5]=f2bf(c.y); v[6]=f2bf(c.z); v[7]=f2bf(c.w);
    size_t dst16 = ((size_t)(m >> 4) * 32 + (hh >> 2)) * 64 + (m & 15) + 16 * (hh & 3);
    *reinterpret_cast<ushort8*>(hbuf0 + dst16 * 8) = v;  // kernel-end flush
}

// ---------------------------------------------------------------------------
// Fused producer-consumer kernel. 256 blocks x 256 threads, 1 block/CU.
//   blocks [0,192):  GEMM producer. Tile tau = mt*32+nt, block g owns
//                    tau = g, g+192, ... (nt = g%32 fixed -> B panel L2-hot).
//                    A,B reg-staged fp32->bf16 into XOR-swizzled LDS.
//                    gx stored sc0sc1 (write-through); per-tile vmcnt(0) +
//                    barrier + device atomicAdd(cnt[mt]); 32nd sets mtdone[mt].
//   blocks [192,256): recurrence consumer (round-10 structure). gx read via
//                    MALL-bypass loads; mtdone[(t+1)>>1] folded into the
//                    per-step h-flag poll (same RTT, no extra serial step).
// No cyclic dependency: producers depend on nothing.
// ---------------------------------------------------------------------------
__global__ __launch_bounds__(256, 1) void k_fused(
        const float* __restrict__ X, const float* __restrict__ Wx,
        const float* __restrict__ bx, const float* __restrict__ bh,
        const float* __restrict__ Wh, const float* __restrict__ cinit,
        float* __restrict__ out, float* __restrict__ gx,
        unsigned short* __restrict__ hbuf, unsigned* __restrict__ bar,
        unsigned* __restrict__ cnt, unsigned* __restrict__ mtdone) {
    __shared__ __align__(16) unsigned short As[128 * 64];  // 16 KB (gemm role)
    __shared__ __align__(16) unsigned short Bs[128 * 64];  // 16 KB (gemm role)
    __shared__ __align__(16) float gs[2][64][68];          // 35 KB (rec role)
    __shared__ __align__(16) unsigned short hs[64][16];    // 2 KB  (rec role)

    const int bid  = blockIdx.x;
    const int tid  = threadIdx.x;
    const int lane = tid & 63;
    const int w    = tid >> 6;
    const int l15  = lane & 15;

    if (bid < NGEMM) {
        // ================= GEMM producer =================
        const int wm   = (w >> 1) * 64;
        const int wn   = (w & 1) * 64;
        const int arow = tid >> 1;        // 0..127
        const int ch   = tid & 1;         // col half (32 elems)
        const int rsw  = (arow & 7) << 4; // write-side XOR swizzle
        const int nt   = bid & 31;        // fixed per block
        char* Adst = (char*)As + arow * 128;
        char* Bdst = (char*)Bs + arow * 128;

        for (int tau = bid; tau < NTILES; tau += NGEMM) {
            const int mt = tau >> 5;
            const float* Abase = X  + (size_t)(mt * 128 + arow) * IDIM + ch * 32;
            const float* Bbase = Wx + (size_t)(nt * 128 + arow) * IDIM + ch * 32;
            f32x4 acc[4][4] = {};

            for (int k0 = 0; k0 < IDIM; k0 += 64) {
                short8 av[4], bv[4];
#pragma unroll
                for (int q = 0; q < 4; ++q) {
                    av[q] = pack8(Abase + k0 + q * 8);
                    bv[q] = pack8(Bbase + k0 + q * 8);
                }
                __syncthreads();          // previous k-step's reads done
#pragma unroll
                for (int q = 0; q < 4; ++q) {
                    const int cb = ch * 64 + q * 16;
                    *reinterpret_cast<short8*>(Adst + (cb ^ rsw)) = av[q];
                    *reinterpret_cast<short8*>(Bdst + (cb ^ rsw)) = bv[q];
                }
                __syncthreads();          // tile staged

                short8 af[2][4], bf_[2][4];
#pragma unroll
                for (int ks = 0; ks < 2; ++ks) {
                    const int cl = ks * 64 + ((lane >> 4) << 4);
#pragma unroll
                    for (int i = 0; i < 4; ++i) {
                        const int ra = wm + i * 16 + l15;
                        af[ks][i] = *reinterpret_cast<const short8*>(
                            (const char*)As + ra * 128 + (cl ^ ((ra & 7) << 4)));
                        const int rb2 = wn + i * 16 + l15;
                        bf_[ks][i] = *reinterpret_cast<const short8*>(
                            (const char*)Bs + rb2 * 128 + (cl ^ ((rb2 & 7) << 4)));
                    }
                }
#pragma unroll
                for (int ks = 0; ks < 2; ++ks)
#pragma unroll
                    for (int i = 0; i < 4; ++i)
#pragma unroll
                        for (int j = 0; j < 4; ++j)
                            acc[i][j] = __builtin_amdgcn_mfma_f32_16x16x32_bf16(
                                af[ks][i], bf_[ks][j], acc[i][j], 0, 0, 0);
            }

            // epilogue: bias + write-through gx stores
#pragma unroll
            for (int j = 0; j < 4; ++j) {
                int n = nt * 128 + wn + j * 16 + l15;
                float bb = bx[n] + bh[n];
#pragma unroll
                for (int i = 0; i < 4; ++i) {
                    int mbase = mt * 128 + wm + i * 16 + (lane >> 4) * 4;
#pragma unroll
                    for (int r = 0; r < 4; ++r)
                        stgf(&gx[(size_t)(mbase + r) * GDIM + n],
                             acc[i][j][r] + bb);
                }
            }
            VMW(0);            // this wave's gx stores at the coherence point
            __syncthreads();   // all 4 waves drained (each waits vmcnt(0))
            if (tid == 0) {
                unsigned old = __hip_atomic_fetch_add(&cnt[mt], 1u,
                                   __ATOMIC_RELAXED, __HIP_MEMORY_SCOPE_AGENT);
                if (old == 31u) stflag(&mtdone[mt * 32], 1u);
            }
        }
        return;
    }

    // ================= recurrence consumer =================
    const int rb  = bid - NGEMM;     // 0..63
    const int rh  = w >> 1;          // batch-row half
    const int kh  = w & 1;           // K half
    const int lk8 = (lane >> 4) * 8;

    // W_h (64 cols x K-half) -> registers
    short8 breg[64];
#pragma unroll
    for (int cg = 0; cg < 4; ++cg) {
        const float* wb = Wh + ((size_t)(cg * HDIM + rb * UPB + l15)) * HDIM
                        + kh * 512 + lk8;
#pragma unroll
        for (int ks = 0; ks < 16; ++ks)
            breg[cg * 16 + ks] = pack8(wb + ks * 32);
    }

    const int m    = tid >> 2;       // batch row 0..63
    const int q    = tid & 3;
    const int u0   = q * 4;
    const int col0 = rb * UPB + u0;

    f32x4 c4 = *reinterpret_cast<const f32x4*>(&cinit[(size_t)m * HDIM + col0]);

    // wait for gx mt=0, then bypass-load gxv for t=0
    {
        unsigned d = ldflag(&mtdone[0]); VMW(0);
        while (!d) {
            __builtin_amdgcn_s_sleep(8);
            d = ldflag(&mtdone[0]); VMW(0);
        }
    }
    f32x4 gxv[4];
#pragma unroll
    for (int g = 0; g < 4; ++g)
        gxv[g] = ldg16f(&gx[(size_t)m * GDIM + g * HDIM + col0]);

    __syncthreads();   // drains gxv/c4 loads: t=0 poll is clean

    // this wave's flag subset: producers [kh*32, kh*32+32)
    const unsigned* fb = &bar[(kh * 32 + (lane & 31)) * 32];

    for (int t = 0; t < T_STEPS; ++t) {
        // ---- poll: h flags >= t AND gx mt for t+1 ready (same RTT)
        {
            int need = (t + 1) >> 1; if (need > 255) need = 255;
            const unsigned* mdp = &mtdone[need * 32];
            while (true) {
                unsigned v = ldflag(fb);
                unsigned d = ldflag(mdp);
                VMW(0);
                if (__all(((int)(v >= (unsigned)t)) & (int)(d != 0))) break;
                __builtin_amdgcn_s_sleep(2);
            }
        }
        asm volatile("" ::: "memory");

        // ---- A stream: disjoint 1KB chunks per wave, 24-deep pipeline
        const unsigned short* hA2 = hbuf + (size_t)(t & 1) * (BATCH * HDIM)
                                  + ((size_t)rh * 64 + kh * 16) * 512 + lane * 8;
        short8 st[24];
#define SLOT(i) ((i) < 24 ? (i) : (i) - 24)
#define ISSK(ks) do { \
        st[SLOT((ks) * 2)]     = ldg16(hA2 + (ks) * 512);          \
        st[SLOT((ks) * 2 + 1)] = ldg16(hA2 + 16384 + (ks) * 512);  \
    } while (0)
#define CONS1(ks) do { \
        short8 a0 = st[SLOT((ks) * 2)], a1 = st[SLOT((ks) * 2 + 1)]; \
        accP0 = __builtin_amdgcn_mfma_f32_16x16x32_bf16(a0, breg[(ks)],      accP0, 0, 0, 0); \
        accP1 = __builtin_amdgcn_mfma_f32_16x16x32_bf16(a0, breg[16 + (ks)], accP1, 0, 0, 0); \
        accP2 = __builtin_amdgcn_mfma_f32_16x16x32_bf16(a0, breg[32 + (ks)], accP2, 0, 0, 0); \
        accP3 = __builtin_amdgcn_mfma_f32_16x16x32_bf16(a0, breg[48 + (ks)], accP3, 0, 0, 0); \
        accQ0 = __builtin_amdgcn_mfma_f32_16x16x32_bf16(a1, breg[(ks)],      accQ0, 0, 0, 0); \
        accQ1 = __builtin_amdgcn_mfma_f32_16x16x32_bf16(a1, breg[16 + (ks)], accQ1, 0, 0, 0); \
        accQ2 = __builtin_amdgcn_mfma_f32_16x16x32_bf16(a1, breg[32 + (ks)], accQ2, 0, 0, 0); \
        accQ3 = __builtin_amdgcn_mfma_f32_16x16x32_bf16(a1, breg[48 + (ks)], accQ3, 0, 0, 0); \
    } while (0)

        f32x4 accP0 = {}, accP1 = {}, accP2 = {}, accP3 = {};
        f32x4 accQ0 = {}, accQ1 = {}, accQ2 = {}, accQ3 = {};
        ISSK(0); ISSK(1); ISSK(2);  ISSK(3);  ISSK(4);  ISSK(5);
        ISSK(6); ISSK(7); ISSK(8);  ISSK(9);  ISSK(10); ISSK(11);
        VMW(16); CONS1(0);  CONS1(1);  CONS1(2);  CONS1(3);
        ISSK(12); ISSK(13); ISSK(14); ISSK(15);
        VMW(16); CONS1(4);  CONS1(5);  CONS1(6);  CONS1(7);
        VMW(8);  CONS1(8);  CONS1(9);  CONS1(10); CONS1(11);
        VMW(0);  CONS1(12); CONS1(13); CONS1(14); CONS1(15);
#undef SLOT
#undef ISSK
#undef CONS1

        // ---- partials -> gs[kh]
        {
            const int gr = rh * 32 + (lane >> 4) * 4;
#pragma unroll
            for (int r = 0; r < 4; ++r) {
                gs[kh][gr + r][l15]           = accP0[r];
                gs[kh][gr + r][16 + l15]      = accP1[r];
                gs[kh][gr + r][32 + l15]      = accP2[r];
                gs[kh][gr + r][48 + l15]      = accP3[r];
                gs[kh][gr + 16 + r][l15]      = accQ0[r];
                gs[kh][gr + 16 + r][16 + l15] = accQ1[r];
                gs[kh][gr + 16 + r][32 + l15] = accQ2[r];
                gs[kh][gr + 16 + r][48 + l15] = accQ3[r];
            }
        }
        __syncthreads();   // joins both kh halves: all 64 flags verified >= t

        // ---- gates + state update: thread = (row m, units u0..u0+3)
        f32x4 hv4;
        {
            f32x4 s0[4], s1[4];
#pragma unroll
            for (int g = 0; g < 4; ++g) {
                s0[g] = *reinterpret_cast<const f32x4*>(&gs[0][m][g * 16 + u0]);
                s1[g] = *reinterpret_cast<const f32x4*>(&gs[1][m][g * 16 + u0]);
            }
#pragma unroll
            for (int j = 0; j < 4; ++j) {
                float xi = gxv[0][j] + s0[0][j] + s1[0][j];
                float xf = gxv[1][j] + s0[1][j] + s1[1][j];
                float xo = gxv[2][j] + s0[2][j] + s1[2][j];
                float xn = gxv[3][j] + s0[3][j] + s1[3][j];
                float ig = fsigmoid(xi);
                float fg = fsigmoid(xf);
                float og = fsigmoid(xo);
                float ng = ftanh(xn);
                c4[j] = fg * c4[j] + ig * ng;
                hv4[j] = og * ftanh(c4[j]);
            }
            unsigned p0 = (unsigned)f2bf(hv4[0]) | ((unsigned)f2bf(hv4[1]) << 16);
            unsigned p1 = (unsigned)f2bf(hv4[2]) | ((unsigned)f2bf(hv4[3]) << 16);
            uint2 pk; pk.x = p0; pk.y = p1;
            *reinterpret_cast<uint2*>(&hs[m][u0]) = pk;
        }

        if (t == T_STEPS - 1) {
            size_t fin = (size_t)T_STEPS * BATCH * HDIM;
            *reinterpret_cast<f32x4*>(
                &out[((size_t)t * BATCH + m) * HDIM + col0]) = hv4;
            *reinterpret_cast<f32x4*>(
                &out[fin + (size_t)m * HDIM + col0]) = hv4;                  // h_fin
            *reinterpret_cast<f32x4*>(
                &out[fin + (size_t)BATCH * HDIM + (size_t)m * HDIM + col0]) = c4; // c_fin
            break;
        }

        __syncthreads();   // hs complete

        // ---- packed swizzled h store -> MALL (128 threads x 16B)
        if (tid < 128) {
            const int mm = tid >> 1;
            const int hh = tid & 1;
            ushort8 v = *reinterpret_cast<const ushort8*>(&hs[mm][hh * 8]);
            size_t dst16 = ((size_t)(mm >> 4) * 32 + (rb >> 1)) * 64 + (mm & 15)
                         + 16 * (((rb & 1) << 1) | hh);
            stg16(hbuf + (size_t)((t + 1) & 1) * (BATCH * HDIM) + dst16 * 8, v);
        }
        __syncthreads();   // per-wave vmcnt(0): h stores at coherence point
        if (tid == 0)
            __hip_atomic_store(&bar[rb * 32], (unsigned)(t + 1),
                               __ATOMIC_RELAXED, __HIP_MEMORY_SCOPE_AGENT);

        // ---- out store + gx bypass prefetch (readiness proven by this
        //      step's poll), then full drain so the next poll is clean
        *reinterpret_cast<f32x4*>(
            &out[((size_t)t * BATCH + m) * HDIM + col0]) = hv4;
        {
            const float* gp = gx + (size_t)(t + 1) * BATCH * GDIM
                            + (size_t)m * GDIM + col0;
#pragma unroll
            for (int g = 0; g < 4; ++g)
                gxv[g] = ldg16f(gp + g * HDIM);
        }
        VMW(0);
    }
}

// ---------------------------------------------------------------------------
extern "C" void kernel_launch(void* const* d_in, const int* in_sizes, int n_in,
                              void* d_out, int out_size, void* d_ws, size_t ws_size,
                              hipStream_t stream) {
    const float* X  = (const float*)d_in[0];
    const float* h0 = (const float*)d_in[1];
    const float* c0 = (const float*)d_in[2];
    const float* Wx = (const float*)d_in[3];
    const float* Wh = (const float*)d_in[4];
    const float* bx = (const float*)d_in[5];
    const float* bh = (const float*)d_in[6];
    float* out = (float*)d_out;

    char* ws = (char*)d_ws;
    float* gx = (float*)ws;                                   // 512 MB fp32
    size_t gx_bytes = (size_t)T_STEPS * BATCH * GDIM * 4;
    unsigned short* hbuf = (unsigned short*)(ws + gx_bytes);  // 2 x 128 KB bf16
    size_t hbuf_bytes = (size_t)2 * BATCH * HDIM * 2;
    char* sync_base = ws + gx_bytes + hbuf_bytes;
    unsigned* bar    = (unsigned*)sync_base;                  // 64 flags @128B
    unsigned* cnt    = (unsigned*)(sync_base + 8192);         // 256 counters
    unsigned* mtdone = (unsigned*)(sync_base + 12288);        // 256 flags @128B

    hipMemsetAsync(sync_base, 0, 45056, stream);
    k_h0_swz<<<dim3(32), dim3(256), 0, stream>>>(h0, hbuf);
    k_fused<<<dim3(NGEMM + NREC), dim3(256), 0, stream>>>(
        X, Wx, bx, bh, Wh, c0, out, gx, hbuf, bar, cnt, mtdone);
}

// Round 14
// 2220.006 us; speedup vs baseline: 1.2789x; 1.0022x over previous
//
#include <hip/hip_runtime.h>
#include <hip/hip_bf16.h>

// Problem constants
#define T_STEPS 512
#define BATCH   64
#define IDIM    1024
#define HDIM    1024
#define GDIM    4096   // 4*HDIM
#define UPB     16     // hidden units per recurrence block
#define NGEMM   192    // producer blocks
#define NREC    64     // consumer (recurrence) blocks
#define NTILES  8192   // (32768/128) * (4096/128)

typedef __attribute__((ext_vector_type(8))) short short8;
typedef __attribute__((ext_vector_type(8))) unsigned short ushort8;
typedef __attribute__((ext_vector_type(4))) float f32x4;

static __device__ __forceinline__ unsigned short f2bf(float f) {
    union { float f; unsigned u; } x; x.f = f;
    unsigned r = x.u + 0x7fffu + ((x.u >> 16) & 1u);  // round-to-nearest-even
    return (unsigned short)(r >> 16);
}

static __device__ __forceinline__ short8 pack8(const float* p) {
    float4 v0 = *reinterpret_cast<const float4*>(p);
    float4 v1 = *reinterpret_cast<const float4*>(p + 4);
    short8 t;
    t[0]=(short)f2bf(v0.x); t[1]=(short)f2bf(v0.y);
    t[2]=(short)f2bf(v0.z); t[3]=(short)f2bf(v0.w);
    t[4]=(short)f2bf(v1.x); t[5]=(short)f2bf(v1.y);
    t[6]=(short)f2bf(v1.z); t[7]=(short)f2bf(v1.w);
    return t;
}

// Coherent-bypass ops (skip L1/L2; MALL coherence point).
static __device__ __forceinline__ short8 ldg16(const unsigned short* p) {
    short8 d;
    asm volatile("global_load_dwordx4 %0, %1, off sc0 sc1" : "=v"(d) : "v"(p));
    return d;
}
static __device__ __forceinline__ f32x4 ldg16f(const float* p) {
    f32x4 d;
    asm volatile("global_load_dwordx4 %0, %1, off sc0 sc1" : "=v"(d) : "v"(p));
    return d;
}
static __device__ __forceinline__ void stg16(unsigned short* p, ushort8 v) {
    asm volatile("global_store_dwordx4 %0, %1, off sc0 sc1"
                 :: "v"(p), "v"(v) : "memory");
}
static __device__ __forceinline__ void stgf(float* p, float v) {
    asm volatile("global_store_dword %0, %1, off sc0 sc1"
                 :: "v"(p), "v"(v) : "memory");
}
static __device__ __forceinline__ unsigned ldflag(const unsigned* p) {
    unsigned d;
    asm volatile("global_load_dword %0, %1, off sc0 sc1" : "=v"(d) : "v"(p));
    return d;
}
static __device__ __forceinline__ void stflag(unsigned* p, unsigned v) {
    asm volatile("global_store_dword %0, %1, off sc0 sc1"
                 :: "v"(p), "v"(v) : "memory");
}

// counted vmcnt wait + scheduler fence
#define VMW(n) do { asm volatile("s_waitcnt vmcnt(" #n ")"); \
                    __builtin_amdgcn_sched_barrier(0); } while (0)

// fast activations
static __device__ __forceinline__ float fexp2(float x) {
    float r; asm("v_exp_f32 %0, %1" : "=v"(r) : "v"(x)); return r;
}
static __device__ __forceinline__ float frcp(float x) {
    float r; asm("v_rcp_f32 %0, %1" : "=v"(r) : "v"(x)); return r;
}
static __device__ __forceinline__ float fsigmoid(float x) {
    return frcp(1.f + fexp2(-1.4426950408889634f * x));
}
static __device__ __forceinline__ float ftanh(float x) {
    return 2.f * frcp(1.f + fexp2(-2.8853900817779268f * x)) - 1.f;
}

// ---------------------------------------------------------------------------
// Kernel 0: h0 (fp32 [B,H]) -> swizzled bf16 buffer 0.
// ---------------------------------------------------------------------------
__global__ void k_h0_swz(const float* __restrict__ h0,
                         unsigned short* __restrict__ hbuf0) {
    int i = blockIdx.x * 256 + threadIdx.x;   // 8192 threads: 64 rows x 128 chunks
    int m  = i >> 7;
    int hh = i & 127;                         // u = hh*8
    const float* src = h0 + (size_t)m * HDIM + hh * 8;
    float4 a = *reinterpret_cast<const float4*>(src);
    float4 c = *reinterpret_cast<const float4*>(src + 4);
    ushort8 v;
    v[0]=f2bf(a.x); v[1]=f2bf(a.y); v[2]=f2bf(a.z); v[3]=f2bf(a.w);
    v[4]=f2bf(c.x); v[5]=f2bf(c.y); v[6]=f2bf(c.z); v[7]=f2bf(c.w);
    size_t dst16 = ((size_t)(m >> 4) * 32 + (hh >> 2)) * 64 + (m & 15) + 16 * (hh & 3);
    *reinterpret_cast<ushort8*>(hbuf0 + dst16 * 8) = v;  // kernel-end flush
}

// ---------------------------------------------------------------------------
// Fused producer-consumer kernel. 256 blocks x 256 threads, 1 block/CU.
//   blocks [0,192):  GEMM producer. Tile tau = mt*32+nt, block g owns
//                    tau = g, g+192, ... (nt = g%32 fixed -> B panel L2-hot).
//                    A,B reg-staged fp32->bf16 into XOR-swizzled LDS.
//                    gx stored sc0sc1 (write-through); per-tile vmcnt(0) +
//                    barrier + device atomicAdd(cnt[mt]); 32nd sets mtdone[mt].
//   blocks [192,256): recurrence consumer (round-10 structure). gx read via
//                    MALL-bypass loads; mtdone[(t+1)>>1] folded into the
//                    per-step h-flag poll (same RTT, no extra serial step).
// No cyclic dependency: producers depend on nothing.
// ---------------------------------------------------------------------------
__global__ __launch_bounds__(256, 1) void k_fused(
        const float* __restrict__ X, const float* __restrict__ Wx,
        const float* __restrict__ bx, const float* __restrict__ bh,
        const float* __restrict__ Wh, const float* __restrict__ cinit,
        float* __restrict__ out, float* __restrict__ gx,
        unsigned short* __restrict__ hbuf, unsigned* __restrict__ bar,
        unsigned* __restrict__ cnt, unsigned* __restrict__ mtdone) {
    __shared__ __align__(16) unsigned short As[128 * 64];  // 16 KB (gemm role)
    __shared__ __align__(16) unsigned short Bs[128 * 64];  // 16 KB (gemm role)
    __shared__ __align__(16) float gs[2][64][68];          // 35 KB (rec role)
    __shared__ __align__(16) unsigned short hs[64][16];    // 2 KB  (rec role)

    const int bid  = blockIdx.x;
    const int tid  = threadIdx.x;
    const int lane = tid & 63;
    const int w    = tid >> 6;
    const int l15  = lane & 15;

    if (bid < NGEMM) {
        // ================= GEMM producer =================
        const int wm   = (w >> 1) * 64;
        const int wn   = (w & 1) * 64;
        const int arow = tid >> 1;        // 0..127
        const int ch   = tid & 1;         // col half (32 elems)
        const int rsw  = (arow & 7) << 4; // write-side XOR swizzle
        const int nt   = bid & 31;        // fixed per block
        char* Adst = (char*)As + arow * 128;
        char* Bdst = (char*)Bs + arow * 128;

        for (int tau = bid; tau < NTILES; tau += NGEMM) {
            const int mt = tau >> 5;
            const float* Abase = X  + (size_t)(mt * 128 + arow) * IDIM + ch * 32;
            const float* Bbase = Wx + (size_t)(nt * 128 + arow) * IDIM + ch * 32;
            f32x4 acc[4][4] = {};

            for (int k0 = 0; k0 < IDIM; k0 += 64) {
                short8 av[4], bv[4];
#pragma unroll
                for (int q = 0; q < 4; ++q) {
                    av[q] = pack8(Abase + k0 + q * 8);
                    bv[q] = pack8(Bbase + k0 + q * 8);
                }
                __syncthreads();          // previous k-step's reads done
#pragma unroll
                for (int q = 0; q < 4; ++q) {
                    const int cb = ch * 64 + q * 16;
                    *reinterpret_cast<short8*>(Adst + (cb ^ rsw)) = av[q];
                    *reinterpret_cast<short8*>(Bdst + (cb ^ rsw)) = bv[q];
                }
                __syncthreads();          // tile staged

                short8 af[2][4], bf_[2][4];
#pragma unroll
                for (int ks = 0; ks < 2; ++ks) {
                    const int cl = ks * 64 + ((lane >> 4) << 4);
#pragma unroll
                    for (int i = 0; i < 4; ++i) {
                        const int ra = wm + i * 16 + l15;
                        af[ks][i] = *reinterpret_cast<const short8*>(
                            (const char*)As + ra * 128 + (cl ^ ((ra & 7) << 4)));
                        const int rb2 = wn + i * 16 + l15;
                        bf_[ks][i] = *reinterpret_cast<const short8*>(
                            (const char*)Bs + rb2 * 128 + (cl ^ ((rb2 & 7) << 4)));
                    }
                }
#pragma unroll
                for (int ks = 0; ks < 2; ++ks)
#pragma unroll
                    for (int i = 0; i < 4; ++i)
#pragma unroll
                        for (int j = 0; j < 4; ++j)
                            acc[i][j] = __builtin_amdgcn_mfma_f32_16x16x32_bf16(
                                af[ks][i], bf_[ks][j], acc[i][j], 0, 0, 0);
            }

            // epilogue: bias + write-through gx stores
#pragma unroll
            for (int j = 0; j < 4; ++j) {
                int n = nt * 128 + wn + j * 16 + l15;
                float bb = bx[n] + bh[n];
#pragma unroll
                for (int i = 0; i < 4; ++i) {
                    int mbase = mt * 128 + wm + i * 16 + (lane >> 4) * 4;
#pragma unroll
                    for (int r = 0; r < 4; ++r)
                        stgf(&gx[(size_t)(mbase + r) * GDIM + n],
                             acc[i][j][r] + bb);
                }
            }
            VMW(0);            // this wave's gx stores at the coherence point
            __syncthreads();   // all 4 waves drained (each waits vmcnt(0))
            if (tid == 0) {
                unsigned old = __hip_atomic_fetch_add(&cnt[mt], 1u,
                                   __ATOMIC_RELAXED, __HIP_MEMORY_SCOPE_AGENT);
                if (old == 31u) stflag(&mtdone[mt * 32], 1u);
            }
        }
        return;
    }

    // ================= recurrence consumer =================
    const int rb  = bid - NGEMM;     // 0..63
    const int rh  = w >> 1;          // batch-row half
    const int kh  = w & 1;           // K half
    const int lk8 = (lane >> 4) * 8;

    // W_h (64 cols x K-half) -> registers
    short8 breg[64];
#pragma unroll
    for (int cg = 0; cg < 4; ++cg) {
        const float* wb = Wh + ((size_t)(cg * HDIM + rb * UPB + l15)) * HDIM
                        + kh * 512 + lk8;
#pragma unroll
        for (int ks = 0; ks < 16; ++ks)
            breg[cg * 16 + ks] = pack8(wb + ks * 32);
    }

    const int m    = tid >> 2;       // batch row 0..63
    const int q    = tid & 3;
    const int u0   = q * 4;
    const int col0 = rb * UPB + u0;

    f32x4 c4 = *reinterpret_cast<const f32x4*>(&cinit[(size_t)m * HDIM + col0]);

    // wait for gx mt=0, then bypass-load gxv for t=0
    {
        unsigned d = ldflag(&mtdone[0]); VMW(0);
        while (!d) {
            __builtin_amdgcn_s_sleep(8);
            d = ldflag(&mtdone[0]); VMW(0);
        }
    }
    f32x4 gxv[4];
#pragma unroll
    for (int g = 0; g < 4; ++g)
        gxv[g] = ldg16f(&gx[(size_t)m * GDIM + g * HDIM + col0]);

    __syncthreads();   // drains gxv/c4 loads: t=0 poll is clean

    // this wave's flag subset: producers [kh*32, kh*32+32)
    const unsigned* fb = &bar[(kh * 32 + (lane & 31)) * 32];

    for (int t = 0; t < T_STEPS; ++t) {
        // ---- poll: h flags >= t AND gx mt for t+1 ready (same RTT)
        {
            int need = (t + 1) >> 1; if (need > 255) need = 255;
            const unsigned* mdp = &mtdone[need * 32];
            while (true) {
                unsigned v = ldflag(fb);
                unsigned d = ldflag(mdp);
                VMW(0);
                if (__all(((int)(v >= (unsigned)t)) & (int)(d != 0))) break;
                __builtin_amdgcn_s_sleep(2);
            }
        }
        asm volatile("" ::: "memory");

        // ---- A stream: disjoint 1KB chunks per wave, 24-deep pipeline
        const unsigned short* hA2 = hbuf + (size_t)(t & 1) * (BATCH * HDIM)
                                  + ((size_t)rh * 64 + kh * 16) * 512 + lane * 8;
        short8 st[24];
#define SLOT(i) ((i) < 24 ? (i) : (i) - 24)
#define ISSK(ks) do { \
        st[SLOT((ks) * 2)]     = ldg16(hA2 + (ks) * 512);          \
        st[SLOT((ks) * 2 + 1)] = ldg16(hA2 + 16384 + (ks) * 512);  \
    } while (0)
#define CONS1(ks) do { \
        short8 a0 = st[SLOT((ks) * 2)], a1 = st[SLOT((ks) * 2 + 1)]; \
        accP0 = __builtin_amdgcn_mfma_f32_16x16x32_bf16(a0, breg[(ks)],      accP0, 0, 0, 0); \
        accP1 = __builtin_amdgcn_mfma_f32_16x16x32_bf16(a0, breg[16 + (ks)], accP1, 0, 0, 0); \
        accP2 = __builtin_amdgcn_mfma_f32_16x16x32_bf16(a0, breg[32 + (ks)], accP2, 0, 0, 0); \
        accP3 = __builtin_amdgcn_mfma_f32_16x16x32_bf16(a0, breg[48 + (ks)], accP3, 0, 0, 0); \
        accQ0 = __builtin_amdgcn_mfma_f32_16x16x32_bf16(a1, breg[(ks)],      accQ0, 0, 0, 0); \
        accQ1 = __builtin_amdgcn_mfma_f32_16x16x32_bf16(a1, breg[16 + (ks)], accQ1, 0, 0, 0); \
        accQ2 = __builtin_amdgcn_mfma_f32_16x16x32_bf16(a1, breg[32 + (ks)], accQ2, 0, 0, 0); \
        accQ3 = __builtin_amdgcn_mfma_f32_16x16x32_bf16(a1, breg[48 + (ks)], accQ3, 0, 0, 0); \
    } while (0)

        f32x4 accP0 = {}, accP1 = {}, accP2 = {}, accP3 = {};
        f32x4 accQ0 = {}, accQ1 = {}, accQ2 = {}, accQ3 = {};
        ISSK(0); ISSK(1); ISSK(2);  ISSK(3);  ISSK(4);  ISSK(5);
        ISSK(6); ISSK(7); ISSK(8);  ISSK(9);  ISSK(10); ISSK(11);
        VMW(16); CONS1(0);  CONS1(1);  CONS1(2);  CONS1(3);
        ISSK(12); ISSK(13); ISSK(14); ISSK(15);
        VMW(16); CONS1(4);  CONS1(5);  CONS1(6);  CONS1(7);
        VMW(8);  CONS1(8);  CONS1(9);  CONS1(10); CONS1(11);
        VMW(0);  CONS1(12); CONS1(13); CONS1(14); CONS1(15);
#undef SLOT
#undef ISSK
#undef CONS1

        // ---- partials -> gs[kh]
        {
            const int gr = rh * 32 + (lane >> 4) * 4;
#pragma unroll
            for (int r = 0; r < 4; ++r) {
                gs[kh][gr + r][l15]           = accP0[r];
                gs[kh][gr + r][16 + l15]      = accP1[r];
                gs[kh][gr + r][32 + l15]      = accP2[r];
                gs[kh][gr + r][48 + l15]      = accP3[r];
                gs[kh][gr + 16 + r][l15]      = accQ0[r];
                gs[kh][gr + 16 + r][16 + l15] = accQ1[r];
                gs[kh][gr + 16 + r][32 + l15] = accQ2[r];
                gs[kh][gr + 16 + r][48 + l15] = accQ3[r];
            }
        }
        __syncthreads();   // joins both kh halves: all 64 flags verified >= t

        // ---- gates + state update: thread = (row m, units u0..u0+3)
        f32x4 hv4;
        {
            f32x4 s0[4], s1[4];
#pragma unroll
            for (int g = 0; g < 4; ++g) {
                s0[g] = *reinterpret_cast<const f32x4*>(&gs[0][m][g * 16 + u0]);
                s1[g] = *reinterpret_cast<const f32x4*>(&gs[1][m][g * 16 + u0]);
            }
#pragma unroll
            for (int j = 0; j < 4; ++j) {
                float xi = gxv[0][j] + s0[0][j] + s1[0][j];
                float xf = gxv[1][j] + s0[1][j] + s1[1][j];
                float xo = gxv[2][j] + s0[2][j] + s1[2][j];
                float xn = gxv[3][j] + s0[3][j] + s1[3][j];
                float ig = fsigmoid(xi);
                float fg = fsigmoid(xf);
                float og = fsigmoid(xo);
                float ng = ftanh(xn);
                c4[j] = fg * c4[j] + ig * ng;
                hv4[j] = og * ftanh(c4[j]);
            }
            unsigned p0 = (unsigned)f2bf(hv4[0]) | ((unsigned)f2bf(hv4[1]) << 16);
            unsigned p1 = (unsigned)f2bf(hv4[2]) | ((unsigned)f2bf(hv4[3]) << 16);
            uint2 pk; pk.x = p0; pk.y = p1;
            *reinterpret_cast<uint2*>(&hs[m][u0]) = pk;
        }

        if (t == T_STEPS - 1) {
            size_t fin = (size_t)T_STEPS * BATCH * HDIM;
            *reinterpret_cast<f32x4*>(
                &out[((size_t)t * BATCH + m) * HDIM + col0]) = hv4;
            *reinterpret_cast<f32x4*>(
                &out[fin + (size_t)m * HDIM + col0]) = hv4;                  // h_fin
            *reinterpret_cast<f32x4*>(
                &out[fin + (size_t)BATCH * HDIM + (size_t)m * HDIM + col0]) = c4; // c_fin
            break;
        }

        __syncthreads();   // hs complete

        // ---- packed swizzled h store -> MALL (128 threads x 16B)
        if (tid < 128) {
            const int mm = tid >> 1;
            const int hh = tid & 1;
            ushort8 v = *reinterpret_cast<const ushort8*>(&hs[mm][hh * 8]);
            size_t dst16 = ((size_t)(mm >> 4) * 32 + (rb >> 1)) * 64 + (mm & 15)
                         + 16 * (((rb & 1) << 1) | hh);
            stg16(hbuf + (size_t)((t + 1) & 1) * (BATCH * HDIM) + dst16 * 8, v);
        }
        __syncthreads();   // per-wave vmcnt(0): h stores at coherence point
        if (tid == 0)
            __hip_atomic_store(&bar[rb * 32], (unsigned)(t + 1),
                               __ATOMIC_RELAXED, __HIP_MEMORY_SCOPE_AGENT);

        // ---- out store + gx bypass prefetch (readiness proven by this
        //      step's poll), then full drain so the next poll is clean
        *reinterpret_cast<f32x4*>(
            &out[((size_t)t * BATCH + m) * HDIM + col0]) = hv4;
        {
            const float* gp = gx + (size_t)(t + 1) * BATCH * GDIM
                            + (size_t)m * GDIM + col0;
#pragma unroll
            for (int g = 0; g < 4; ++g)
                gxv[g] = ldg16f(gp + g * HDIM);
        }
        VMW(0);
    }
}

// ---------------------------------------------------------------------------
extern "C" void kernel_launch(void* const* d_in, const int* in_sizes, int n_in,
                              void* d_out, int out_size, void* d_ws, size_t ws_size,
                              hipStream_t stream) {
    const float* X  = (const float*)d_in[0];
    const float* h0 = (const float*)d_in[1];
    const float* c0 = (const float*)d_in[2];
    const float* Wx = (const float*)d_in[3];
    const float* Wh = (const float*)d_in[4];
    const float* bx = (const float*)d_in[5];
    const float* bh = (const float*)d_in[6];
    float* out = (float*)d_out;

    char* ws = (char*)d_ws;
    float* gx = (float*)ws;                                   // 512 MB fp32
    size_t gx_bytes = (size_t)T_STEPS * BATCH * GDIM * 4;
    unsigned short* hbuf = (unsigned short*)(ws + gx_bytes);  // 2 x 128 KB bf16
    size_t hbuf_bytes = (size_t)2 * BATCH * HDIM * 2;
    char* sync_base = ws + gx_bytes + hbuf_bytes;
    unsigned* bar    = (unsigned*)sync_base;                  // 64 flags @128B
    unsigned* cnt    = (unsigned*)(sync_base + 8192);         // 256 counters
    unsigned* mtdone = (unsigned*)(sync_base + 12288);        // 256 flags @128B

    hipMemsetAsync(sync_base, 0, 45056, stream);
    k_h0_swz<<<dim3(32), dim3(256), 0, stream>>>(h0, hbuf);
    k_fused<<<dim3(NGEMM + NREC), dim3(256), 0, stream>>>(
        X, Wx, bx, bh, Wh, c0, out, gx, hbuf, bar, cnt, mtdone);
}